// Round 1
// baseline (5348.365 us; speedup 1.0000x reference)
//
#include <hip/hip_runtime.h>
#include <hip/hip_bf16.h>

#define B_   4
#define T_   2048
#define C_   1024
#define H_   16
#define DH_  64
#define BT_  (B_ * T_)      // 8192
#define NQKV (3 * C_)       // 3072

__device__ inline float toF(float x) { return x; }
__device__ inline float toF(__hip_bfloat16 x) { return __bfloat162float(x); }
__device__ inline void storeT(float* p, float v) { *p = v; }
__device__ inline void storeT(__hip_bfloat16* p, float v) { *p = __float2bfloat16(v); }

// C[m][n] = sum_k A[m][k] * Bw[n][k]   (A: MxK row-major, Bw: NxK row-major)
template <typename TA, typename TO>
__global__ __launch_bounds__(256) void gemm_bt(const TA* __restrict__ A,
                                               const float* __restrict__ Bw,
                                               TO* __restrict__ Cm,
                                               int M, int N, int K) {
    __shared__ float As[16][65];
    __shared__ float Bs[16][65];
    const int tid = threadIdx.x;
    const int tx = tid & 15, ty = tid >> 4;
    const int m0 = blockIdx.x * 64;
    const int n0 = blockIdx.y * 64;
    const int kload = tid & 15;
    const int rbase = tid >> 4;
    float acc[4][4] = {};
    for (int k0 = 0; k0 < K; k0 += 16) {
#pragma unroll
        for (int r = 0; r < 4; ++r) {
            int mm = rbase + r * 16;
            As[kload][mm] = toF(A[(size_t)(m0 + mm) * K + k0 + kload]);
            Bs[kload][mm] = Bw[(size_t)(n0 + mm) * K + k0 + kload];
        }
        __syncthreads();
#pragma unroll
        for (int kk = 0; kk < 16; ++kk) {
            float a[4], b[4];
#pragma unroll
            for (int i = 0; i < 4; ++i) a[i] = As[kk][ty * 4 + i];
#pragma unroll
            for (int j = 0; j < 4; ++j) b[j] = Bs[kk][tx * 4 + j];
#pragma unroll
            for (int i = 0; i < 4; ++i)
#pragma unroll
                for (int j = 0; j < 4; ++j) acc[i][j] += a[i] * b[j];
        }
        __syncthreads();
    }
#pragma unroll
    for (int i = 0; i < 4; ++i)
#pragma unroll
        for (int j = 0; j < 4; ++j) {
            int m = m0 + ty * 4 + i, n = n0 + tx * 4 + j;
            storeT(&Cm[(size_t)m * N + n], acc[i][j]);
        }
}

// RoPE in-place on Q (cols 0..1023) and K (cols 1024..2047) of qkv (BT_ x 3072)
__global__ __launch_bounds__(256) void rope_kernel(__hip_bfloat16* qkv) {
    int idx = blockIdx.x * 256 + threadIdx.x;  // one per even/odd pair
    const int totalPairs = BT_ * 1024;         // 8192 * (2048/2)
    if (idx >= totalPairs) return;
    int pair = idx & 1023;
    int row = idx >> 10;
    int col = pair * 2;            // 0..2046 (covers Q and K regions)
    int d = col & 63;              // within-head dim (even)
    int i = d >> 1;
    float pos = (float)(row & (T_ - 1));
    float inv = expf(-((float)(2 * i) / 64.0f) * 9.2103403719761836f);  // theta=1e4
    float ang = pos * inv;
    float s, c;
    sincosf(ang, &s, &c);
    size_t base = (size_t)row * NQKV + col;
    float x1 = __bfloat162float(qkv[base]);
    float x2 = __bfloat162float(qkv[base + 1]);
    qkv[base]     = __float2bfloat16(x1 * c - x2 * s);
    qkv[base + 1] = __float2bfloat16(x1 * s + x2 * c);
}

// Flash-style causal attention. One block = (b, h, 32-row q tile). 256 threads.
__global__ __launch_bounds__(256) void attn_kernel(const __hip_bfloat16* __restrict__ qkv,
                                                   __hip_bfloat16* __restrict__ att) {
    const int blk = blockIdx.x;
    const int qt = blk & 63;       // T_/32 = 64 tiles
    const int bh = blk >> 6;
    const int b = bh >> 4, h = bh & 15;
    const int q0 = qt * 32;
    const int tid = threadIdx.x;

    __shared__ float Qs[32][65], Ks[32][65], Vs[32][65];
    __shared__ float Ss[32][33];
    __shared__ float red[32][8];
    __shared__ float mrow[32], lrow[32], arow[32];

    {   // load Q tile, pre-scaled by 1/sqrt(Dh)
        int d = tid & 63, i0 = tid >> 6;  // i0: 0..3
        const size_t base = (size_t)(b * T_ + q0) * NQKV + h * 64;
#pragma unroll
        for (int r = 0; r < 8; ++r) {
            int i = i0 + r * 4;
            Qs[i][d] = 0.125f * __bfloat162float(qkv[base + (size_t)i * NQKV + d]);
        }
    }
    if (tid < 32) { mrow[tid] = -1e30f; lrow[tid] = 0.0f; }
    float acc[8] = {};
    const int r_row = tid >> 3, r_u = tid & 7;
    __syncthreads();

    for (int k0 = 0; k0 <= q0; k0 += 32) {
        {   // load K, V tiles
            int d = tid & 63, i0 = tid >> 6;
            const size_t kb = (size_t)(b * T_ + k0) * NQKV + C_ + h * 64;
            const size_t vb = kb + C_;
#pragma unroll
            for (int r = 0; r < 8; ++r) {
                int i = i0 + r * 4;
                Ks[i][d] = __bfloat162float(qkv[kb + (size_t)i * NQKV + d]);
                Vs[i][d] = __bfloat162float(qkv[vb + (size_t)i * NQKV + d]);
            }
        }
        __syncthreads();
        {   // S = Q K^T with causal mask
            int j = tid & 31, ib = tid >> 5;  // ib: 0..7
#pragma unroll
            for (int rr = 0; rr < 4; ++rr) {
                int i = ib + rr * 8;
                float s = 0.f;
#pragma unroll
                for (int d = 0; d < 64; ++d) s += Qs[i][d] * Ks[j][d];
                if (k0 + j > q0 + i) s = -1e30f;
                Ss[i][j] = s;
            }
        }
        __syncthreads();
        {   // partial row max
            float pm = -1e30f;
            for (int jj = r_u; jj < 32; jj += 8) pm = fmaxf(pm, Ss[r_row][jj]);
            red[r_row][r_u] = pm;
        }
        __syncthreads();
        if (r_u == 0) {
            float rm = red[r_row][0];
#pragma unroll
            for (int u = 1; u < 8; ++u) rm = fmaxf(rm, red[r_row][u]);
            float mn = fmaxf(mrow[r_row], rm);
            arow[r_row] = expf(mrow[r_row] - mn);
            mrow[r_row] = mn;
        }
        __syncthreads();
        {   // P = exp(S - m), partial row sum
            float ps = 0.f;
            float mn = mrow[r_row];
            for (int jj = r_u; jj < 32; jj += 8) {
                float p = expf(Ss[r_row][jj] - mn);
                Ss[r_row][jj] = p;
                ps += p;
            }
            red[r_row][r_u] = ps;
        }
        __syncthreads();
        if (r_u == 0) {
            float rs = 0.f;
#pragma unroll
            for (int u = 0; u < 8; ++u) rs += red[r_row][u];
            lrow[r_row] = lrow[r_row] * arow[r_row] + rs;
        }
        {   // acc = acc*alpha + P @ V  (this thread: row r_row, dims r_u*8..r_u*8+7)
            float a = arow[r_row];
#pragma unroll
            for (int dd = 0; dd < 8; ++dd) acc[dd] *= a;
            for (int j = 0; j < 32; ++j) {
                float p = Ss[r_row][j];
#pragma unroll
                for (int dd = 0; dd < 8; ++dd) acc[dd] += p * Vs[j][r_u * 8 + dd];
            }
        }
        __syncthreads();
    }
    {   // epilogue: att[(b,q), h*64+d] = acc / l
        float inv = 1.0f / lrow[r_row];
        size_t ob = (size_t)(b * T_ + q0 + r_row) * C_ + h * 64 + r_u * 8;
#pragma unroll
        for (int dd = 0; dd < 8; ++dd)
            att[ob + dd] = __float2bfloat16(acc[dd] * inv);
    }
}

extern "C" void kernel_launch(void* const* d_in, const int* in_sizes, int n_in,
                              void* d_out, int out_size, void* d_ws, size_t ws_size,
                              hipStream_t stream) {
    const float* x = (const float*)d_in[0];
    const float* Wqkv = (const float*)d_in[1];
    const float* Wproj = (const float*)d_in[2];
    float* out = (float*)d_out;

    __hip_bfloat16* qkv = (__hip_bfloat16*)d_ws;                          // 8192x3072 bf16 = 48 MB
    __hip_bfloat16* att = (__hip_bfloat16*)((char*)d_ws + (size_t)BT_ * NQKV * 2);  // 16 MB

    // 1) qkv = x @ Wqkv^T   (M=8192, N=3072, K=1024)
    dim3 g1(BT_ / 64, NQKV / 64);
    gemm_bt<float, __hip_bfloat16><<<g1, 256, 0, stream>>>(x, Wqkv, qkv, BT_, NQKV, C_);

    // 2) RoPE on Q,K
    int pairs = BT_ * 1024;
    rope_kernel<<<(pairs + 255) / 256, 256, 0, stream>>>(qkv);

    // 3) causal attention
    attn_kernel<<<B_ * H_ * (T_ / 32), 256, 0, stream>>>(qkv, att);

    // 4) out = att @ Wproj^T  (M=8192, N=1024, K=1024)
    dim3 g2(BT_ / 64, C_ / 64);
    gemm_bt<__hip_bfloat16, float><<<g2, 256, 0, stream>>>(att, Wproj, out, BT_, C_, C_);
}

// Round 3
// 461.468 us; speedup vs baseline: 11.5899x; 11.5899x over previous
//
#include <hip/hip_runtime.h>
#include <hip/hip_bf16.h>

#define B_   4
#define T_   2048
#define C_   1024
#define H_   16
#define BT_  (B_ * T_)      // 8192
#define NQKV (3 * C_)       // 3072

typedef __attribute__((ext_vector_type(8))) short short8;
typedef __attribute__((ext_vector_type(4))) float f32x4;

__device__ inline float b2f(short u) {
    unsigned int x = ((unsigned int)(unsigned short)u) << 16;
    float f;
    __builtin_memcpy(&f, &x, 4);
    return f;
}
__device__ inline short f2b(float f) {
    __hip_bfloat16 h = __float2bfloat16(f);
    unsigned short u;
    __builtin_memcpy(&u, &h, 2);
    return (short)u;
}
__device__ inline f32x4 fz4() { f32x4 z; z[0] = z[1] = z[2] = z[3] = 0.f; return z; }

__device__ inline void load_lds16(const void* g, void* l) {
    __builtin_amdgcn_global_load_lds((const __attribute__((address_space(1))) unsigned int*)g,
                                     (__attribute__((address_space(3))) unsigned int*)l,
                                     16, 0, 0);
}

// fp32 -> bf16 bulk convert (n multiple of 2048)
__global__ __launch_bounds__(256) void cvt_kernel(const float* __restrict__ in,
                                                  short* __restrict__ out, int n) {
    int i = (blockIdx.x * 256 + threadIdx.x) * 8;
    if (i >= n) return;
    float4 a = *(const float4*)(in + i);
    float4 b = *(const float4*)(in + i + 4);
    short8 s;
    s[0] = f2b(a.x); s[1] = f2b(a.y); s[2] = f2b(a.z); s[3] = f2b(a.w);
    s[4] = f2b(b.x); s[5] = f2b(b.y); s[6] = f2b(b.z); s[7] = f2b(b.w);
    *(short8*)(out + i) = s;
}

// C[m][n] = sum_k A[m][k] * Bw[n][k]; Bw bf16 [N][K]. 128x128 tile, BK=64, 4 waves.
// m97-verified structure: linear LDS, global_load_lds width 16, 2-barrier K loop.
template <int AFP32, int CF32>
__global__ __launch_bounds__(256) void gemm_mfma(const void* __restrict__ Ap,
                                                 const short* __restrict__ Bw,
                                                 void* __restrict__ Cp,
                                                 int M, int N, int K) {
    __shared__ short As[128 * 64];
    __shared__ short Bs[128 * 64];
    const int tid = threadIdx.x;
    const int l16 = tid & 15, lq = (tid & 63) >> 4;
    const int wid = tid >> 6;
    const int wm = wid >> 1, wn = wid & 1;
    const int m0 = blockIdx.x * 128, n0 = blockIdx.y * 128;

    f32x4 acc[4][4];
#pragma unroll
    for (int i = 0; i < 4; ++i)
#pragma unroll
        for (int j = 0; j < 4; ++j) acc[i][j] = fz4();

    for (int k0 = 0; k0 < K; k0 += 64) {
        // stage B: 1024 chunks of 16B; LDS linear (chunk c at byte c*16)
#pragma unroll
        for (int i = 0; i < 4; ++i) {
            int c = i * 256 + tid;
            int r = c >> 3, col = c & 7;
            load_lds16(Bw + (size_t)(n0 + r) * K + k0 + col * 8,
                       &Bs[i * 2048 + (tid & ~63) * 8]);
        }
        if constexpr (AFP32) {
            const float* Af = (const float*)Ap;
#pragma unroll
            for (int i = 0; i < 4; ++i) {
                int c = i * 256 + tid;
                int r = c >> 3, col = c & 7;
                const float* g = Af + (size_t)(m0 + r) * K + k0 + col * 8;
                float4 f0 = *(const float4*)g;
                float4 f1 = *(const float4*)(g + 4);
                short8 s;
                s[0] = f2b(f0.x); s[1] = f2b(f0.y); s[2] = f2b(f0.z); s[3] = f2b(f0.w);
                s[4] = f2b(f1.x); s[5] = f2b(f1.y); s[6] = f2b(f1.z); s[7] = f2b(f1.w);
                *(short8*)&As[r * 64 + col * 8] = s;
            }
        } else {
            const short* Ab = (const short*)Ap;
#pragma unroll
            for (int i = 0; i < 4; ++i) {
                int c = i * 256 + tid;
                int r = c >> 3, col = c & 7;
                load_lds16(Ab + (size_t)(m0 + r) * K + k0 + col * 8,
                           &As[i * 2048 + (tid & ~63) * 8]);
            }
        }
        __syncthreads();
#pragma unroll
        for (int kk = 0; kk < 2; ++kk) {
            short8 af[4], bf[4];
#pragma unroll
            for (int mf = 0; mf < 4; ++mf)
                af[mf] = *(const short8*)&As[(wm * 64 + mf * 16 + l16) * 64 + (kk * 4 + lq) * 8];
#pragma unroll
            for (int nf = 0; nf < 4; ++nf)
                bf[nf] = *(const short8*)&Bs[(wn * 64 + nf * 16 + l16) * 64 + (kk * 4 + lq) * 8];
#pragma unroll
            for (int mf = 0; mf < 4; ++mf)
#pragma unroll
                for (int nf = 0; nf < 4; ++nf)
                    acc[mf][nf] = __builtin_amdgcn_mfma_f32_16x16x32_bf16(
                        af[mf], bf[nf], acc[mf][nf], 0, 0, 0);
        }
        __syncthreads();
    }
#pragma unroll
    for (int mf = 0; mf < 4; ++mf)
#pragma unroll
        for (int nf = 0; nf < 4; ++nf)
#pragma unroll
            for (int rr = 0; rr < 4; ++rr) {
                int row = m0 + wm * 64 + mf * 16 + lq * 4 + rr;
                int col = n0 + wn * 64 + nf * 16 + l16;
                if constexpr (CF32)
                    ((float*)Cp)[(size_t)row * N + col] = acc[mf][nf][rr];
                else
                    ((short*)Cp)[(size_t)row * N + col] = f2b(acc[mf][nf][rr]);
            }
}

// RoPE in-place on Q (cols 0..1023) and K (cols 1024..2047) of bf16 qkv
__global__ __launch_bounds__(256) void rope_kernel(short* qkv) {
    int idx = blockIdx.x * 256 + threadIdx.x;
    int pair = idx & 1023;
    int row = idx >> 10;
    int col = pair * 2;
    int i = (col & 63) >> 1;
    float pos = (float)(row & (T_ - 1));
    float inv = expf(-((float)(2 * i) / 64.0f) * 9.2103403719761836f);
    float ang = pos * inv;
    float s, c;
    sincosf(ang, &s, &c);
    size_t base = (size_t)row * NQKV + col;
    float x1 = b2f(qkv[base]);
    float x2 = b2f(qkv[base + 1]);
    qkv[base]     = f2b(x1 * c - x2 * s);
    qkv[base + 1] = f2b(x1 * s + x2 * c);
}

// MFMA flash attention: block = (b,h,64 q rows), 4 waves x 16 rows, KV tile 64.
// V staged TRANSPOSED in LDS (Vt[d][kv]) so PV B-fragments are contiguous reads.
__global__ __launch_bounds__(256) void attn_mfma(const short* __restrict__ qkv,
                                                 short* __restrict__ att) {
    const int blk = blockIdx.x;
    const int qt = blk & 31;          // T/64
    const int bh = blk >> 5;
    const int b = bh >> 4, h = bh & 15;
    const int q0 = qt * 64;
    const int tid = threadIdx.x;
    const int w = tid >> 6, l = tid & 63;
    const int l16 = l & 15, lq = l >> 4;

    __shared__ short Ks[64][72];      // K row-major, padded pitch 144B
    __shared__ short Vt[64][72];      // V transposed: Vt[d][kv]
    __shared__ short Ps[4][16][72];   // per-wave P (A-layout staging)

    // Q fragments (pre-scaled by 1/sqrt(64))
    short8 qf[2];
    {
        const size_t qrow = (size_t)((b * T_) + q0 + w * 16 + l16) * NQKV + h * 64;
#pragma unroll
        for (int kk = 0; kk < 2; ++kk) {
            short8 raw = *(const short8*)(qkv + qrow + kk * 32 + lq * 8);
            short8 s;
#pragma unroll
            for (int j = 0; j < 8; ++j) s[j] = f2b(0.125f * b2f(raw[j]));
            qf[kk] = s;
        }
    }
    f32x4 acc[4];
#pragma unroll
    for (int dt = 0; dt < 4; ++dt) acc[dt] = fz4();
    float m_r[4], l_r[4];
#pragma unroll
    for (int r = 0; r < 4; ++r) { m_r[r] = -1e30f; l_r[r] = 0.f; }

    const int nt = qt + 1;
    for (int t = 0; t < nt; ++t) {
        const int k0 = t * 64;
        {   // stage K (row-major) and V (transposed scatter)
            const size_t kb = (size_t)((b * T_) + k0) * NQKV + C_ + h * 64;
#pragma unroll
            for (int p = 0; p < 2; ++p) {
                int c = p * 256 + tid;
                int kv = c >> 3, d0 = (c & 7) * 8;
                *(short8*)&Ks[kv][d0] = *(const short8*)(qkv + kb + (size_t)kv * NQKV + d0);
            }
#pragma unroll
            for (int p = 0; p < 2; ++p) {
                int c = p * 256 + tid;
                int kv = c >> 3, d0 = (c & 7) * 8;
                short8 v = *(const short8*)(qkv + kb + C_ + (size_t)kv * NQKV + d0);
#pragma unroll
                for (int u = 0; u < 8; ++u) Vt[d0 + u][kv] = v[u];
            }
        }
        __syncthreads();
        // S = Q K^T
        f32x4 sc[4];
#pragma unroll
        for (int ct = 0; ct < 4; ++ct) sc[ct] = fz4();
#pragma unroll
        for (int kk = 0; kk < 2; ++kk)
#pragma unroll
            for (int ct = 0; ct < 4; ++ct) {
                short8 bk = *(const short8*)&Ks[ct * 16 + l16][kk * 32 + lq * 8];
                sc[ct] = __builtin_amdgcn_mfma_f32_16x16x32_bf16(qf[kk], bk, sc[ct], 0, 0, 0);
            }
        // causal mask (skip for fully-valid tiles)
        const int rowg = q0 + w * 16 + lq * 4;
        if (k0 + 63 > q0 + w * 16) {
#pragma unroll
            for (int ct = 0; ct < 4; ++ct)
#pragma unroll
                for (int r = 0; r < 4; ++r)
                    if (k0 + ct * 16 + l16 > rowg + r) sc[ct][r] = -1e30f;
        }
        // online softmax (each row lives across the 16 lanes of a quadrant)
        float al[4];
#pragma unroll
        for (int r = 0; r < 4; ++r) {
            float mx = fmaxf(fmaxf(sc[0][r], sc[1][r]), fmaxf(sc[2][r], sc[3][r]));
            mx = fmaxf(mx, __shfl_xor(mx, 1));
            mx = fmaxf(mx, __shfl_xor(mx, 2));
            mx = fmaxf(mx, __shfl_xor(mx, 4));
            mx = fmaxf(mx, __shfl_xor(mx, 8));
            float mn = fmaxf(m_r[r], mx);
            al[r] = __expf(m_r[r] - mn);
            m_r[r] = mn;
            float s0 = 0.f;
#pragma unroll
            for (int ct = 0; ct < 4; ++ct) {
                float p = __expf(sc[ct][r] - mn);
                sc[ct][r] = p;
                s0 += p;
            }
            s0 += __shfl_xor(s0, 1);
            s0 += __shfl_xor(s0, 2);
            s0 += __shfl_xor(s0, 4);
            s0 += __shfl_xor(s0, 8);
            l_r[r] = l_r[r] * al[r] + s0;
        }
#pragma unroll
        for (int dt = 0; dt < 4; ++dt) {
            f32x4 a4 = acc[dt];
            a4[0] *= al[0]; a4[1] *= al[1]; a4[2] *= al[2]; a4[3] *= al[3];
            acc[dt] = a4;
        }
        // P -> per-wave LDS (D-layout to A-layout transpose)
#pragma unroll
        for (int ct = 0; ct < 4; ++ct)
#pragma unroll
            for (int r = 0; r < 4; ++r)
                Ps[w][lq * 4 + r][ct * 16 + l16] = f2b(sc[ct][r]);
        // O += P V : A = P (16x64), B-fragment from Vt contiguous
#pragma unroll
        for (int kk = 0; kk < 2; ++kk) {
            short8 pa = *(const short8*)&Ps[w][l16][kk * 32 + lq * 8];
#pragma unroll
            for (int dt = 0; dt < 4; ++dt) {
                short8 bv = *(const short8*)&Vt[dt * 16 + l16][kk * 32 + lq * 8];
                acc[dt] = __builtin_amdgcn_mfma_f32_16x16x32_bf16(pa, bv, acc[dt], 0, 0, 0);
            }
        }
        __syncthreads();
    }
    // epilogue
#pragma unroll
    for (int r = 0; r < 4; ++r) {
        float inv = 1.0f / l_r[r];
        size_t ob = (size_t)((b * T_) + q0 + w * 16 + lq * 4 + r) * C_ + h * 64 + l16;
#pragma unroll
        for (int dt = 0; dt < 4; ++dt)
            att[ob + dt * 16] = f2b(acc[dt][r] * inv);
    }
}

extern "C" void kernel_launch(void* const* d_in, const int* in_sizes, int n_in,
                              void* d_out, int out_size, void* d_ws, size_t ws_size,
                              hipStream_t stream) {
    const float* x = (const float*)d_in[0];
    const float* Wqkv = (const float*)d_in[1];
    const float* Wproj = (const float*)d_in[2];
    float* out = (float*)d_out;
    char* ws = (char*)d_ws;

    short* qkv = (short*)ws;                                   // [0, 48MB)
    short* att = (short*)(ws + (size_t)BT_ * NQKV * 2);        // [48MB, 64MB)
    short* wqb = att;                                          // 6MB, dead before att written
    short* wpb = qkv;                                          // 2MB, qkv dead by then

    // 1) Wqkv -> bf16
    cvt_kernel<<<(3 * C_ * C_) / 2048, 256, 0, stream>>>(Wqkv, wqb, 3 * C_ * C_);
    // 2) qkv = x @ Wqkv^T (bf16 out)
    dim3 g1(BT_ / 128, NQKV / 128);
    gemm_mfma<1, 0><<<g1, 256, 0, stream>>>((const void*)x, wqb, (void*)qkv, BT_, NQKV, C_);
    // 3) RoPE on Q,K
    rope_kernel<<<(BT_ * 1024) / 256, 256, 0, stream>>>(qkv);
    // 4) attention
    attn_mfma<<<B_ * H_ * (T_ / 64), 256, 0, stream>>>(qkv, att);
    // 5) Wproj -> bf16
    cvt_kernel<<<(C_ * C_) / 2048, 256, 0, stream>>>(Wproj, wpb, C_ * C_);
    // 6) out = att @ Wproj^T (fp32 out)
    dim3 g2(BT_ / 128, C_ / 128);
    gemm_mfma<0, 1><<<g2, 256, 0, stream>>>((const void*)att, wpb, (void*)out, BT_, C_, C_);
}

// Round 4
// 266.933 us; speedup vs baseline: 20.0364x; 1.7288x over previous
//
#include <hip/hip_runtime.h>
#include <hip/hip_bf16.h>

#define B_   4
#define T_   2048
#define C_   1024
#define H_   16
#define BT_  (B_ * T_)      // 8192
#define NQKV (3 * C_)       // 3072

typedef __attribute__((ext_vector_type(8))) short short8;
typedef __attribute__((ext_vector_type(4))) float f32x4;

__device__ inline float b2f(short u) {
    unsigned int x = ((unsigned int)(unsigned short)u) << 16;
    float f;
    __builtin_memcpy(&f, &x, 4);
    return f;
}
__device__ inline short f2b(float f) {
    __hip_bfloat16 h = __float2bfloat16(f);
    unsigned short u;
    __builtin_memcpy(&u, &h, 2);
    return (short)u;
}
__device__ inline f32x4 fz4() { f32x4 z; z[0] = z[1] = z[2] = z[3] = 0.f; return z; }

__device__ inline void load_lds16(const void* g, void* l) {
    __builtin_amdgcn_global_load_lds((const __attribute__((address_space(1))) unsigned int*)g,
                                     (__attribute__((address_space(3))) unsigned int*)l,
                                     16, 0, 0);
}

// fp32 -> bf16 bulk convert (n multiple of 2048)
__global__ __launch_bounds__(256) void cvt_kernel(const float* __restrict__ in,
                                                  short* __restrict__ out, int n) {
    int i = (blockIdx.x * 256 + threadIdx.x) * 8;
    if (i >= n) return;
    float4 a = *(const float4*)(in + i);
    float4 b = *(const float4*)(in + i + 4);
    short8 s;
    s[0] = f2b(a.x); s[1] = f2b(a.y); s[2] = f2b(a.z); s[3] = f2b(a.w);
    s[4] = f2b(b.x); s[5] = f2b(b.y); s[6] = f2b(b.z); s[7] = f2b(b.w);
    *(short8*)(out + i) = s;
}

// C[m][n] = sum_k A[m][k] * Bw[n][k]; Bw bf16 [N][K]. 128x128 tile, BK=64, 4 waves.
// m97-verified structure: linear LDS, global_load_lds width 16, 2-barrier K loop.
template <int AFP32, int CF32>
__global__ __launch_bounds__(256) void gemm_mfma(const void* __restrict__ Ap,
                                                 const short* __restrict__ Bw,
                                                 void* __restrict__ Cp,
                                                 int M, int N, int K) {
    __shared__ short As[128 * 64];
    __shared__ short Bs[128 * 64];
    const int tid = threadIdx.x;
    const int l16 = tid & 15, lq = (tid & 63) >> 4;
    const int wid = tid >> 6;
    const int wm = wid >> 1, wn = wid & 1;
    const int m0 = blockIdx.x * 128, n0 = blockIdx.y * 128;

    f32x4 acc[4][4];
#pragma unroll
    for (int i = 0; i < 4; ++i)
#pragma unroll
        for (int j = 0; j < 4; ++j) acc[i][j] = fz4();

    for (int k0 = 0; k0 < K; k0 += 64) {
#pragma unroll
        for (int i = 0; i < 4; ++i) {
            int c = i * 256 + tid;
            int r = c >> 3, col = c & 7;
            load_lds16(Bw + (size_t)(n0 + r) * K + k0 + col * 8,
                       &Bs[i * 2048 + (tid & ~63) * 8]);
        }
        if constexpr (AFP32) {
            const float* Af = (const float*)Ap;
#pragma unroll
            for (int i = 0; i < 4; ++i) {
                int c = i * 256 + tid;
                int r = c >> 3, col = c & 7;
                const float* g = Af + (size_t)(m0 + r) * K + k0 + col * 8;
                float4 f0 = *(const float4*)g;
                float4 f1 = *(const float4*)(g + 4);
                short8 s;
                s[0] = f2b(f0.x); s[1] = f2b(f0.y); s[2] = f2b(f0.z); s[3] = f2b(f0.w);
                s[4] = f2b(f1.x); s[5] = f2b(f1.y); s[6] = f2b(f1.z); s[7] = f2b(f1.w);
                *(short8*)&As[r * 64 + col * 8] = s;
            }
        } else {
            const short* Ab = (const short*)Ap;
#pragma unroll
            for (int i = 0; i < 4; ++i) {
                int c = i * 256 + tid;
                int r = c >> 3, col = c & 7;
                load_lds16(Ab + (size_t)(m0 + r) * K + k0 + col * 8,
                           &As[i * 2048 + (tid & ~63) * 8]);
            }
        }
        __syncthreads();
#pragma unroll
        for (int kk = 0; kk < 2; ++kk) {
            short8 af[4], bf[4];
#pragma unroll
            for (int mf = 0; mf < 4; ++mf)
                af[mf] = *(const short8*)&As[(wm * 64 + mf * 16 + l16) * 64 + (kk * 4 + lq) * 8];
#pragma unroll
            for (int nf = 0; nf < 4; ++nf)
                bf[nf] = *(const short8*)&Bs[(wn * 64 + nf * 16 + l16) * 64 + (kk * 4 + lq) * 8];
#pragma unroll
            for (int mf = 0; mf < 4; ++mf)
#pragma unroll
                for (int nf = 0; nf < 4; ++nf)
                    acc[mf][nf] = __builtin_amdgcn_mfma_f32_16x16x32_bf16(
                        af[mf], bf[nf], acc[mf][nf], 0, 0, 0);
        }
        __syncthreads();
    }
#pragma unroll
    for (int mf = 0; mf < 4; ++mf)
#pragma unroll
        for (int nf = 0; nf < 4; ++nf)
#pragma unroll
            for (int rr = 0; rr < 4; ++rr) {
                int row = m0 + wm * 64 + mf * 16 + lq * 4 + rr;
                int col = n0 + wn * 64 + nf * 16 + l16;
                if constexpr (CF32)
                    ((float*)Cp)[(size_t)row * N + col] = acc[mf][nf][rr];
                else
                    ((short*)Cp)[(size_t)row * N + col] = f2b(acc[mf][nf][rr]);
            }
}

// RoPE in-place on Q (cols 0..1023) and K (cols 1024..2047) of bf16 qkv
__global__ __launch_bounds__(256) void rope_kernel(short* qkv) {
    int idx = blockIdx.x * 256 + threadIdx.x;
    int pair = idx & 1023;
    int row = idx >> 10;
    int col = pair * 2;
    int i = (col & 63) >> 1;
    float pos = (float)(row & (T_ - 1));
    float inv = exp2f(-(float)i * 0.41524101186092029f);   // 10000^(-i/32)
    float ang = pos * inv;
    float s, c;
    sincosf(ang, &s, &c);
    size_t base = (size_t)row * NQKV + col;
    float x1 = b2f(qkv[base]);
    float x2 = b2f(qkv[base + 1]);
    qkv[base]     = f2b(x1 * c - x2 * s);
    qkv[base + 1] = f2b(x1 * s + x2 * c);
}

// MFMA flash attention: block = (b,h,64 q rows), 4 waves x 16 rows, KV tile 64.
// Swapped QK^T: sc = mfma(K,Q) = S^T, so each lane owns one q-row (l16) and the
// softmax reduce is 2 shfl_xor (16,32) instead of a depth-8 chain per row.
__global__ __launch_bounds__(256) void attn_mfma(const short* __restrict__ qkv,
                                                 short* __restrict__ att) {
    const int blk = blockIdx.x;
    const int bh = blk & 63;               // all heads of a qt dispatch together
    const int qt = 31 - (blk >> 6);        // heavy q-tiles first
    const int b = bh >> 4, h = bh & 15;
    const int q0 = qt * 64;
    const int tid = threadIdx.x;
    const int w = tid >> 6, l = tid & 63;
    const int l16 = l & 15, lq = l >> 4;

    __shared__ short Ks[64][72];      // K row-major, padded pitch 144B
    __shared__ short Vt[64][72];      // V transposed: Vt[d][kv]
    __shared__ short Ps[4][16][72];   // per-wave P (A-layout staging)

    // Q fragments (pre-scaled by 1/sqrt(64))
    short8 qf[2];
    {
        const size_t qrow = (size_t)((b * T_) + q0 + w * 16 + l16) * NQKV + h * 64;
#pragma unroll
        for (int kk = 0; kk < 2; ++kk) {
            short8 raw = *(const short8*)(qkv + qrow + kk * 32 + lq * 8);
            short8 s;
#pragma unroll
            for (int j = 0; j < 8; ++j) s[j] = f2b(0.125f * b2f(raw[j]));
            qf[kk] = s;
        }
    }
    f32x4 acc[4];
#pragma unroll
    for (int dt = 0; dt < 4; ++dt) acc[dt] = fz4();
    float m_s = -1e30f, l_s = 0.f;    // per-lane: stats of q-row l16

    const int nt = qt + 1;
    for (int t = 0; t < nt; ++t) {
        const int k0 = t * 64;
        {   // stage K (row-major) and V (transposed scatter)
            const size_t kb = (size_t)((b * T_) + k0) * NQKV + C_ + h * 64;
#pragma unroll
            for (int p = 0; p < 2; ++p) {
                int c = p * 256 + tid;
                int kv = c >> 3, d0 = (c & 7) * 8;
                *(short8*)&Ks[kv][d0] = *(const short8*)(qkv + kb + (size_t)kv * NQKV + d0);
            }
#pragma unroll
            for (int p = 0; p < 2; ++p) {
                int c = p * 256 + tid;
                int kv = c >> 3, d0 = (c & 7) * 8;
                short8 v = *(const short8*)(qkv + kb + C_ + (size_t)kv * NQKV + d0);
#pragma unroll
                for (int u = 0; u < 8; ++u) Vt[d0 + u][kv] = v[u];
            }
        }
        __syncthreads();
        // S^T = K Q^T : lane holds S[k = ct*16+lq*4+r][q = l16]
        f32x4 sc[4];
#pragma unroll
        for (int ct = 0; ct < 4; ++ct) sc[ct] = fz4();
        __builtin_amdgcn_s_setprio(1);
#pragma unroll
        for (int kk = 0; kk < 2; ++kk)
#pragma unroll
            for (int ct = 0; ct < 4; ++ct) {
                short8 ak = *(const short8*)&Ks[ct * 16 + l16][kk * 32 + lq * 8];
                sc[ct] = __builtin_amdgcn_mfma_f32_16x16x32_bf16(ak, qf[kk], sc[ct], 0, 0, 0);
            }
        __builtin_amdgcn_s_setprio(0);
        // causal mask (skip for fully-valid tiles)
        const int qg = q0 + w * 16 + l16;
        if (k0 + 63 > q0 + w * 16) {
#pragma unroll
            for (int ct = 0; ct < 4; ++ct)
#pragma unroll
                for (int r = 0; r < 4; ++r)
                    if (k0 + ct * 16 + lq * 4 + r > qg) sc[ct][r] = -1e30f;
        }
        // online softmax: lane-local over 16 values, then xor-16/32 across lq groups
        float mx = -1e30f;
#pragma unroll
        for (int ct = 0; ct < 4; ++ct)
#pragma unroll
            for (int r = 0; r < 4; ++r) mx = fmaxf(mx, sc[ct][r]);
        mx = fmaxf(mx, __shfl_xor(mx, 16));
        mx = fmaxf(mx, __shfl_xor(mx, 32));
        float mn = fmaxf(m_s, mx);
        float al = __expf(m_s - mn);
        m_s = mn;
        float s0 = 0.f;
#pragma unroll
        for (int ct = 0; ct < 4; ++ct)
#pragma unroll
            for (int r = 0; r < 4; ++r) {
                float p = __expf(sc[ct][r] - mn);
                sc[ct][r] = p;
                s0 += p;
            }
        s0 += __shfl_xor(s0, 16);
        s0 += __shfl_xor(s0, 32);
        l_s = l_s * al + s0;
        // rescale acc: acc rows are q = lq*4+r, alphas live at lanes 0..15
        float albc[4];
#pragma unroll
        for (int r = 0; r < 4; ++r) albc[r] = __shfl(al, lq * 4 + r);
#pragma unroll
        for (int dt = 0; dt < 4; ++dt) {
            f32x4 a4 = acc[dt];
            a4[0] *= albc[0]; a4[1] *= albc[1]; a4[2] *= albc[2]; a4[3] *= albc[3];
            acc[dt] = a4;
        }
        // P -> per-wave LDS: P[q=l16][k=ct*16+lq*4+r]
#pragma unroll
        for (int ct = 0; ct < 4; ++ct)
#pragma unroll
            for (int r = 0; r < 4; ++r)
                Ps[w][l16][ct * 16 + lq * 4 + r] = f2b(sc[ct][r]);
        // O += P V : A-frag from Ps, B-frag from Vt (both contiguous)
        __builtin_amdgcn_s_setprio(1);
#pragma unroll
        for (int kk = 0; kk < 2; ++kk) {
            short8 pa = *(const short8*)&Ps[w][l16][kk * 32 + lq * 8];
#pragma unroll
            for (int dt = 0; dt < 4; ++dt) {
                short8 bv = *(const short8*)&Vt[dt * 16 + l16][kk * 32 + lq * 8];
                acc[dt] = __builtin_amdgcn_mfma_f32_16x16x32_bf16(pa, bv, acc[dt], 0, 0, 0);
            }
        }
        __builtin_amdgcn_s_setprio(0);
        __syncthreads();
    }
    // epilogue: l for q-row lq*4+r lives at lane lq*4+r
    float lbc[4];
#pragma unroll
    for (int r = 0; r < 4; ++r) lbc[r] = __shfl(l_s, lq * 4 + r);
#pragma unroll
    for (int r = 0; r < 4; ++r) {
        float inv = 1.0f / lbc[r];
        size_t ob = (size_t)((b * T_) + q0 + w * 16 + lq * 4 + r) * C_ + h * 64 + l16;
#pragma unroll
        for (int dt = 0; dt < 4; ++dt)
            att[ob + dt * 16] = f2b(acc[dt][r] * inv);
    }
}

extern "C" void kernel_launch(void* const* d_in, const int* in_sizes, int n_in,
                              void* d_out, int out_size, void* d_ws, size_t ws_size,
                              hipStream_t stream) {
    const float* x = (const float*)d_in[0];
    const float* Wqkv = (const float*)d_in[1];
    const float* Wproj = (const float*)d_in[2];
    float* out = (float*)d_out;
    char* ws = (char*)d_ws;

    short* qkv = (short*)ws;                                   // [0, 48MB)
    short* att = (short*)(ws + (size_t)BT_ * NQKV * 2);        // [48MB, 64MB)
    short* wqb = att;                                          // 6MB, dead before att written
    short* wpb = qkv;                                          // 2MB, qkv dead by then

    // 1) Wqkv -> bf16
    cvt_kernel<<<(3 * C_ * C_) / 2048, 256, 0, stream>>>(Wqkv, wqb, 3 * C_ * C_);
    // 2) qkv = x @ Wqkv^T (bf16 out)
    dim3 g1(BT_ / 128, NQKV / 128);
    gemm_mfma<1, 0><<<g1, 256, 0, stream>>>((const void*)x, wqb, (void*)qkv, BT_, NQKV, C_);
    // 3) RoPE on Q,K
    rope_kernel<<<(BT_ * 1024) / 256, 256, 0, stream>>>(qkv);
    // 4) attention
    attn_mfma<<<B_ * H_ * (T_ / 64), 256, 0, stream>>>(qkv, att);
    // 5) Wproj -> bf16
    cvt_kernel<<<(C_ * C_) / 2048, 256, 0, stream>>>(Wproj, wpb, C_ * C_);
    // 6) out = att @ Wproj^T (fp32 out)
    dim3 g2(BT_ / 128, C_ / 128);
    gemm_mfma<0, 1><<<g2, 256, 0, stream>>>((const void*)att, wpb, (void*)out, BT_, C_, C_);
}

// Round 5
// 224.982 us; speedup vs baseline: 23.7725x; 1.1865x over previous
//
#include <hip/hip_runtime.h>
#include <hip/hip_bf16.h>

#define B_   4
#define T_   2048
#define C_   1024
#define H_   16
#define BT_  (B_ * T_)      // 8192
#define NQKV (3 * C_)       // 3072

typedef __attribute__((ext_vector_type(8))) short short8;
typedef __attribute__((ext_vector_type(4))) float f32x4;

__device__ inline float b2f(short u) {
    unsigned int x = ((unsigned int)(unsigned short)u) << 16;
    float f;
    __builtin_memcpy(&f, &x, 4);
    return f;
}
__device__ inline short f2b(float f) {
    __hip_bfloat16 h = __float2bfloat16(f);
    unsigned short u;
    __builtin_memcpy(&u, &h, 2);
    return (short)u;
}
__device__ inline f32x4 fz4() { f32x4 z; z[0] = z[1] = z[2] = z[3] = 0.f; return z; }

__device__ inline void load_lds16(const void* g, void* l) {
    __builtin_amdgcn_global_load_lds((const __attribute__((address_space(1))) unsigned int*)g,
                                     (__attribute__((address_space(3))) unsigned int*)l,
                                     16, 0, 0);
}

// fp32 -> bf16 bulk convert (n multiple of 2048)
__global__ __launch_bounds__(256) void cvt_kernel(const float* __restrict__ in,
                                                  short* __restrict__ out, int n) {
    int i = (blockIdx.x * 256 + threadIdx.x) * 8;
    if (i >= n) return;
    float4 a = *(const float4*)(in + i);
    float4 b = *(const float4*)(in + i + 4);
    short8 s;
    s[0] = f2b(a.x); s[1] = f2b(a.y); s[2] = f2b(a.z); s[3] = f2b(a.w);
    s[4] = f2b(b.x); s[5] = f2b(b.y); s[6] = f2b(b.z); s[7] = f2b(b.w);
    *(short8*)(out + i) = s;
}

// C[m][n] = sum_k A[m][k] * Bw[n][k]; Bw bf16 [N][K]. 128x128 tile, BK=64, 4 waves.
template <int AFP32, int CF32>
__global__ __launch_bounds__(256) void gemm_mfma(const void* __restrict__ Ap,
                                                 const short* __restrict__ Bw,
                                                 void* __restrict__ Cp,
                                                 int M, int N, int K) {
    __shared__ short As[128 * 64];
    __shared__ short Bs[128 * 64];
    const int tid = threadIdx.x;
    const int l16 = tid & 15, lq = (tid & 63) >> 4;
    const int wid = tid >> 6;
    const int wm = wid >> 1, wn = wid & 1;
    const int m0 = blockIdx.x * 128, n0 = blockIdx.y * 128;

    f32x4 acc[4][4];
#pragma unroll
    for (int i = 0; i < 4; ++i)
#pragma unroll
        for (int j = 0; j < 4; ++j) acc[i][j] = fz4();

    for (int k0 = 0; k0 < K; k0 += 64) {
#pragma unroll
        for (int i = 0; i < 4; ++i) {
            int c = i * 256 + tid;
            int r = c >> 3, col = c & 7;
            load_lds16(Bw + (size_t)(n0 + r) * K + k0 + col * 8,
                       &Bs[i * 2048 + (tid & ~63) * 8]);
        }
        if constexpr (AFP32) {
            const float* Af = (const float*)Ap;
#pragma unroll
            for (int i = 0; i < 4; ++i) {
                int c = i * 256 + tid;
                int r = c >> 3, col = c & 7;
                const float* g = Af + (size_t)(m0 + r) * K + k0 + col * 8;
                float4 f0 = *(const float4*)g;
                float4 f1 = *(const float4*)(g + 4);
                short8 s;
                s[0] = f2b(f0.x); s[1] = f2b(f0.y); s[2] = f2b(f0.z); s[3] = f2b(f0.w);
                s[4] = f2b(f1.x); s[5] = f2b(f1.y); s[6] = f2b(f1.z); s[7] = f2b(f1.w);
                *(short8*)&As[r * 64 + col * 8] = s;
            }
        } else {
            const short* Ab = (const short*)Ap;
#pragma unroll
            for (int i = 0; i < 4; ++i) {
                int c = i * 256 + tid;
                int r = c >> 3, col = c & 7;
                load_lds16(Ab + (size_t)(m0 + r) * K + k0 + col * 8,
                           &As[i * 2048 + (tid & ~63) * 8]);
            }
        }
        __syncthreads();
#pragma unroll
        for (int kk = 0; kk < 2; ++kk) {
            short8 af[4], bf[4];
#pragma unroll
            for (int mf = 0; mf < 4; ++mf)
                af[mf] = *(const short8*)&As[(wm * 64 + mf * 16 + l16) * 64 + (kk * 4 + lq) * 8];
#pragma unroll
            for (int nf = 0; nf < 4; ++nf)
                bf[nf] = *(const short8*)&Bs[(wn * 64 + nf * 16 + l16) * 64 + (kk * 4 + lq) * 8];
#pragma unroll
            for (int mf = 0; mf < 4; ++mf)
#pragma unroll
                for (int nf = 0; nf < 4; ++nf)
                    acc[mf][nf] = __builtin_amdgcn_mfma_f32_16x16x32_bf16(
                        af[mf], bf[nf], acc[mf][nf], 0, 0, 0);
        }
        __syncthreads();
    }
#pragma unroll
    for (int mf = 0; mf < 4; ++mf)
#pragma unroll
        for (int nf = 0; nf < 4; ++nf)
#pragma unroll
            for (int rr = 0; rr < 4; ++rr) {
                int row = m0 + wm * 64 + mf * 16 + lq * 4 + rr;
                int col = n0 + wn * 64 + nf * 16 + l16;
                if constexpr (CF32)
                    ((float*)Cp)[(size_t)row * N + col] = acc[mf][nf][rr];
                else
                    ((short*)Cp)[(size_t)row * N + col] = f2b(acc[mf][nf][rr]);
            }
}

// RoPE in-place on Q (cols 0..1023) and K (cols 1024..2047) of bf16 qkv
__global__ __launch_bounds__(256) void rope_kernel(short* qkv) {
    int idx = blockIdx.x * 256 + threadIdx.x;
    int pair = idx & 1023;
    int row = idx >> 10;
    int col = pair * 2;
    int i = (col & 63) >> 1;
    float pos = (float)(row & (T_ - 1));
    float inv = exp2f(-(float)i * 0.41524101186092029f);   // 10000^(-i/32)
    float ang = pos * inv;
    float s, c;
    sincosf(ang, &s, &c);
    size_t base = (size_t)row * NQKV + col;
    float x1 = b2f(qkv[base]);
    float x2 = b2f(qkv[base + 1]);
    qkv[base]     = f2b(x1 * c - x2 * s);
    qkv[base + 1] = f2b(x1 * s + x2 * c);
}

// V region of qkv -> vT[(b*16+h)*64 + d][t]  (per-(b,h) 64 x 2048, bf16)
__global__ __launch_bounds__(256) void transpose_v(const short* __restrict__ qkv,
                                                   short* __restrict__ vT) {
    const int blk = blockIdx.x;
    const int bh = blk >> 5, tt = blk & 31;
    const int b = bh >> 4, h = bh & 15;
    const int t0 = tt * 64;
    const int tid = threadIdx.x;
    __shared__ int tile[64][65];
#pragma unroll
    for (int p = 0; p < 2; ++p) {
        int c = p * 256 + tid;
        int t = c >> 3, d0 = (c & 7) * 8;
        short8 v = *(const short8*)(qkv + (size_t)(b * T_ + t0 + t) * NQKV + 2 * C_ + h * 64 + d0);
#pragma unroll
        for (int u = 0; u < 8; ++u) tile[t][d0 + u] = v[u];
    }
    __syncthreads();
#pragma unroll
    for (int p = 0; p < 2; ++p) {
        int c = p * 256 + tid;
        int d = c >> 3, tq0 = (c & 7) * 8;
        short8 s;
#pragma unroll
        for (int u = 0; u < 8; ++u) s[u] = (short)tile[tq0 + u][d];
        *(short8*)(vT + (size_t)(bh * 64 + d) * 2048 + t0 + tq0) = s;
    }
}

// MFMA flash attention: block = (b,h,128 q rows), 4 waves, each wave 2 groups of 16 rows.
// K/V staged via global_load_lds with pre-swizzled source; all LDS tiles are
// [row][64] bf16 (128B pitch) with 16B-chunk XOR swizzle chunk^=(row&7).
__global__ __launch_bounds__(256) void attn_mfma(const short* __restrict__ qkv,
                                                 const short* __restrict__ vT,
                                                 short* __restrict__ att) {
    const int blk = blockIdx.x;
    const int bh = blk & 63;               // all heads of a qt dispatch together
    const int qt = 15 - (blk >> 6);        // heavy q-tiles first
    const int b = bh >> 4, h = bh & 15;
    const int q0 = qt * 128;
    const int tid = threadIdx.x;
    const int w = tid >> 6, l = tid & 63;
    const int l16 = l & 15, lq = l >> 4;
    const int e = l16 & 7;                 // row-XOR term for fragment reads

    __shared__ short Ks[64 * 64];
    __shared__ short Vs[64 * 64];
    __shared__ short Ps[4][16 * 64];

    // Q fragments for both row-groups (pre-scaled by 1/sqrt(64))
    short8 qf[2][2];
#pragma unroll
    for (int rg = 0; rg < 2; ++rg) {
        const size_t qrow = (size_t)((b * T_) + q0 + rg * 64 + w * 16 + l16) * NQKV + h * 64;
#pragma unroll
        for (int kk = 0; kk < 2; ++kk) {
            short8 raw = *(const short8*)(qkv + qrow + kk * 32 + lq * 8);
            short8 s;
#pragma unroll
            for (int j = 0; j < 8; ++j) s[j] = f2b(0.125f * b2f(raw[j]));
            qf[rg][kk] = s;
        }
    }
    f32x4 acc[2][4];
#pragma unroll
    for (int rg = 0; rg < 2; ++rg)
#pragma unroll
        for (int dt = 0; dt < 4; ++dt) acc[rg][dt] = fz4();
    float m_s[2] = {-1e30f, -1e30f}, l_s[2] = {0.f, 0.f};

    const int nt = 2 * qt + 2;
    for (int t = 0; t < nt; ++t) {
        const int k0 = t * 64;
        {   // stage K from qkv, V from vT; linear LDS dest, swizzled global chunk
            const size_t kbase = (size_t)((b * T_) + k0) * NQKV + C_ + h * 64;
            const size_t vbase = (size_t)(bh * 64) * 2048 + k0;
#pragma unroll
            for (int p = 0; p < 2; ++p) {
                int c = p * 256 + tid;
                int r = c >> 3;
                int cg = (c & 7) ^ (r & 7);
                load_lds16(qkv + kbase + (size_t)r * NQKV + cg * 8,
                           &Ks[p * 2048 + (tid & ~63) * 8]);
                load_lds16(vT + vbase + (size_t)r * 2048 + cg * 8,
                           &Vs[p * 2048 + (tid & ~63) * 8]);
            }
        }
        __syncthreads();
#pragma unroll
        for (int rg = 0; rg < 2; ++rg) {
            if (rg == 0 && t == nt - 1) continue;   // block-uniform skip
            const int qg = q0 + rg * 64 + w * 16 + l16;
            // S^T = K Q^T : lane holds S[k = ct*16+lq*4+r][q = l16]
            f32x4 sc[4];
#pragma unroll
            for (int ct = 0; ct < 4; ++ct) sc[ct] = fz4();
            __builtin_amdgcn_s_setprio(1);
#pragma unroll
            for (int kk = 0; kk < 2; ++kk)
#pragma unroll
                for (int ct = 0; ct < 4; ++ct) {
                    short8 ak = *(const short8*)&Ks[(ct * 16 + l16) * 64 + (((kk * 4 + lq) ^ e) * 8)];
                    sc[ct] = __builtin_amdgcn_mfma_f32_16x16x32_bf16(ak, qf[rg][kk], sc[ct], 0, 0, 0);
                }
            __builtin_amdgcn_s_setprio(0);
            // causal mask (skip for fully-valid tiles)
            if (k0 + 63 > q0 + rg * 64 + w * 16) {
#pragma unroll
                for (int ct = 0; ct < 4; ++ct)
#pragma unroll
                    for (int r = 0; r < 4; ++r)
                        if (k0 + ct * 16 + lq * 4 + r > qg) sc[ct][r] = -1e30f;
            }
            // online softmax: lane-local 16 values, xor-16/32 across lq groups
            float mx = -1e30f;
#pragma unroll
            for (int ct = 0; ct < 4; ++ct)
#pragma unroll
                for (int r = 0; r < 4; ++r) mx = fmaxf(mx, sc[ct][r]);
            mx = fmaxf(mx, __shfl_xor(mx, 16));
            mx = fmaxf(mx, __shfl_xor(mx, 32));
            float mn = fmaxf(m_s[rg], mx);
            float al = __expf(m_s[rg] - mn);
            m_s[rg] = mn;
            float s0 = 0.f;
#pragma unroll
            for (int ct = 0; ct < 4; ++ct)
#pragma unroll
                for (int r = 0; r < 4; ++r) {
                    float p = __expf(sc[ct][r] - mn);
                    sc[ct][r] = p;
                    s0 += p;
                }
            s0 += __shfl_xor(s0, 16);
            s0 += __shfl_xor(s0, 32);
            l_s[rg] = l_s[rg] * al + s0;
            // rescale acc rows (q = lq*4+r), alphas live at lanes 0..15
            float albc[4];
#pragma unroll
            for (int r = 0; r < 4; ++r) albc[r] = __shfl(al, lq * 4 + r);
#pragma unroll
            for (int dt = 0; dt < 4; ++dt) {
                f32x4 a4 = acc[rg][dt];
                a4[0] *= albc[0]; a4[1] *= albc[1]; a4[2] *= albc[2]; a4[3] *= albc[3];
                acc[rg][dt] = a4;
            }
            // P -> per-wave LDS (swizzled): row q=l16, k chunk-XOR'd
#pragma unroll
            for (int ct = 0; ct < 4; ++ct)
#pragma unroll
                for (int r = 0; r < 4; ++r) {
                    int k = ct * 16 + lq * 4 + r;
                    Ps[w][l16 * 64 + (((k >> 3) ^ e) * 8) + (k & 7)] = f2b(sc[ct][r]);
                }
            // O += P V
            __builtin_amdgcn_s_setprio(1);
#pragma unroll
            for (int kk = 0; kk < 2; ++kk) {
                short8 pa = *(const short8*)&Ps[w][l16 * 64 + (((kk * 4 + lq) ^ e) * 8)];
#pragma unroll
                for (int dt = 0; dt < 4; ++dt) {
                    short8 bv = *(const short8*)&Vs[(dt * 16 + l16) * 64 + (((kk * 4 + lq) ^ e) * 8)];
                    acc[rg][dt] = __builtin_amdgcn_mfma_f32_16x16x32_bf16(pa, bv, acc[rg][dt], 0, 0, 0);
                }
            }
            __builtin_amdgcn_s_setprio(0);
        }
        __syncthreads();
    }
    // epilogue: l for q-row lq*4+r lives at lane lq*4+r
#pragma unroll
    for (int rg = 0; rg < 2; ++rg) {
        float lbc[4];
#pragma unroll
        for (int r = 0; r < 4; ++r) lbc[r] = __shfl(l_s[rg], lq * 4 + r);
#pragma unroll
        for (int r = 0; r < 4; ++r) {
            float inv = 1.0f / lbc[r];
            size_t ob = (size_t)((b * T_) + q0 + rg * 64 + w * 16 + lq * 4 + r) * C_ + h * 64 + l16;
#pragma unroll
            for (int dt = 0; dt < 4; ++dt)
                att[ob + dt * 16] = f2b(acc[rg][dt][r] * inv);
        }
    }
}

extern "C" void kernel_launch(void* const* d_in, const int* in_sizes, int n_in,
                              void* d_out, int out_size, void* d_ws, size_t ws_size,
                              hipStream_t stream) {
    const float* x = (const float*)d_in[0];
    const float* Wqkv = (const float*)d_in[1];
    const float* Wproj = (const float*)d_in[2];
    float* out = (float*)d_out;
    char* ws = (char*)d_ws;

    short* qkv = (short*)ws;                                   // [0, 48MB)
    short* att = (short*)(ws + (size_t)BT_ * NQKV * 2);        // [48MB, 64MB)
    short* wqb = att;                                          // 6MB, dead before att written
    short* wpb = qkv;                                          // 2MB, qkv dead by then
    short* vT  = (short*)d_out;                                // 16MB scratch; out written only by final GEMM

    // 1) Wqkv -> bf16
    cvt_kernel<<<(3 * C_ * C_) / 2048, 256, 0, stream>>>(Wqkv, wqb, 3 * C_ * C_);
    // 2) qkv = x @ Wqkv^T (bf16 out)
    dim3 g1(BT_ / 128, NQKV / 128);
    gemm_mfma<1, 0><<<g1, 256, 0, stream>>>((const void*)x, wqb, (void*)qkv, BT_, NQKV, C_);
    // 3) RoPE on Q,K
    rope_kernel<<<(BT_ * 1024) / 256, 256, 0, stream>>>(qkv);
    // 4) V -> vT (per-(b,h) transpose)
    transpose_v<<<64 * 32, 256, 0, stream>>>(qkv, vT);
    // 5) attention
    attn_mfma<<<B_ * H_ * (T_ / 128), 256, 0, stream>>>(qkv, vT, att);
    // 6) Wproj -> bf16
    cvt_kernel<<<(C_ * C_) / 2048, 256, 0, stream>>>(Wproj, wpb, C_ * C_);
    // 7) out = att @ Wproj^T (fp32 out)
    dim3 g2(BT_ / 128, C_ / 128);
    gemm_mfma<0, 1><<<g2, 256, 0, stream>>>((const void*)att, wpb, (void*)out, BT_, C_, C_);
}

// Round 6
// 216.796 us; speedup vs baseline: 24.6700x; 1.0378x over previous
//
#include <hip/hip_runtime.h>
#include <hip/hip_bf16.h>

#define B_   4
#define T_   2048
#define C_   1024
#define H_   16
#define BT_  (B_ * T_)      // 8192
#define NQKV (3 * C_)       // 3072

typedef __attribute__((ext_vector_type(8))) short short8;
typedef __attribute__((ext_vector_type(4))) float f32x4;

__device__ inline float b2f(short u) {
    unsigned int x = ((unsigned int)(unsigned short)u) << 16;
    float f;
    __builtin_memcpy(&f, &x, 4);
    return f;
}
__device__ inline short f2b(float f) {
    __hip_bfloat16 h = __float2bfloat16(f);
    unsigned short u;
    __builtin_memcpy(&u, &h, 2);
    return (short)u;
}
__device__ inline f32x4 fz4() { f32x4 z; z[0] = z[1] = z[2] = z[3] = 0.f; return z; }

__device__ inline void load_lds16(const void* g, void* l) {
    __builtin_amdgcn_global_load_lds((const __attribute__((address_space(1))) unsigned int*)g,
                                     (__attribute__((address_space(3))) unsigned int*)l,
                                     16, 0, 0);
}

// fp32 -> bf16 bulk convert (n multiple of 2048)
__global__ __launch_bounds__(256) void cvt_kernel(const float* __restrict__ in,
                                                  short* __restrict__ out, int n) {
    int i = (blockIdx.x * 256 + threadIdx.x) * 8;
    if (i >= n) return;
    float4 a = *(const float4*)(in + i);
    float4 b = *(const float4*)(in + i + 4);
    short8 s;
    s[0] = f2b(a.x); s[1] = f2b(a.y); s[2] = f2b(a.z); s[3] = f2b(a.w);
    s[4] = f2b(b.x); s[5] = f2b(b.y); s[6] = f2b(b.z); s[7] = f2b(b.w);
    *(short8*)(out + i) = s;
}

// cos/sin table: tab[t*32+i] = (cos, sin) of t * 10000^(-i/32), t<2048, i<32
__global__ __launch_bounds__(256) void rope_table(float2* __restrict__ tab) {
    int idx = blockIdx.x * 256 + threadIdx.x;   // 65536
    int t = idx >> 5, i = idx & 31;
    float inv = exp2f(-(float)i * 0.41524101186092029f);
    float ang = (float)t * inv;
    float s, c;
    sincosf(ang, &s, &c);
    tab[idx] = make_float2(c, s);
}

// C[m][n] = sum_k A[m][k] * Bw[n][k]; Bw bf16 [N][K]. 128x128 tile, BK=64, 4 waves.
// T3-min double-buffer: stage(t+1) issued before compute(t); one drain+barrier per K-step.
// ROPE: fused rotary on fp32 acc for cols < 2048 (pair exchange via shfl_xor 1).
template <int AFP32, int CF32, int ROPE>
__global__ __launch_bounds__(256) void gemm_mfma(const void* __restrict__ Ap,
                                                 const short* __restrict__ Bw,
                                                 void* __restrict__ Cp,
                                                 int M, int N, int K,
                                                 const float2* __restrict__ tab) {
    __shared__ short As[2][128 * 64];
    __shared__ short Bs[2][128 * 64];
    const int tid = threadIdx.x;
    const int l16 = tid & 15, lq = (tid & 63) >> 4;
    const int wid = tid >> 6;
    const int wm = wid >> 1, wn = wid & 1;
    const int m0 = blockIdx.x * 128, n0 = blockIdx.y * 128;

    f32x4 acc[4][4];
#pragma unroll
    for (int i = 0; i < 4; ++i)
#pragma unroll
        for (int j = 0; j < 4; ++j) acc[i][j] = fz4();

    const int NT = K >> 6;

    // ---- stage tile t into buffer b ----
    auto stage = [&](int bf, int t) {
        const int k0 = t * 64;
#pragma unroll
        for (int i = 0; i < 4; ++i) {
            int c = i * 256 + tid;
            int r = c >> 3, col = c & 7;
            load_lds16(Bw + (size_t)(n0 + r) * K + k0 + col * 8,
                       &Bs[bf][i * 2048 + (tid & ~63) * 8]);
        }
        if constexpr (AFP32) {
            const float* Af = (const float*)Ap;
#pragma unroll
            for (int i = 0; i < 4; ++i) {
                int c = i * 256 + tid;
                int r = c >> 3, col = c & 7;
                const float* g = Af + (size_t)(m0 + r) * K + k0 + col * 8;
                float4 f0 = *(const float4*)g;
                float4 f1 = *(const float4*)(g + 4);
                short8 s;
                s[0] = f2b(f0.x); s[1] = f2b(f0.y); s[2] = f2b(f0.z); s[3] = f2b(f0.w);
                s[4] = f2b(f1.x); s[5] = f2b(f1.y); s[6] = f2b(f1.z); s[7] = f2b(f1.w);
                *(short8*)&As[bf][r * 64 + col * 8] = s;
            }
        } else {
            const short* Ab = (const short*)Ap;
#pragma unroll
            for (int i = 0; i < 4; ++i) {
                int c = i * 256 + tid;
                int r = c >> 3, col = c & 7;
                load_lds16(Ab + (size_t)(m0 + r) * K + k0 + col * 8,
                           &As[bf][i * 2048 + (tid & ~63) * 8]);
            }
        }
    };

    // prologue
    stage(0, 0);
    asm volatile("s_waitcnt vmcnt(0) lgkmcnt(0)" ::: "memory");
    __builtin_amdgcn_s_barrier();
    __builtin_amdgcn_sched_barrier(0);

    int cur = 0;
    for (int t = 0; t < NT; ++t) {
        if (t + 1 < NT) stage(cur ^ 1, t + 1);
#pragma unroll
        for (int kk = 0; kk < 2; ++kk) {
            short8 af[4], bf[4];
#pragma unroll
            for (int mf = 0; mf < 4; ++mf)
                af[mf] = *(const short8*)&As[cur][(wm * 64 + mf * 16 + l16) * 64 + (kk * 4 + lq) * 8];
#pragma unroll
            for (int nf = 0; nf < 4; ++nf)
                bf[nf] = *(const short8*)&Bs[cur][(wn * 64 + nf * 16 + l16) * 64 + (kk * 4 + lq) * 8];
            __builtin_amdgcn_s_setprio(1);
#pragma unroll
            for (int mf = 0; mf < 4; ++mf)
#pragma unroll
                for (int nf = 0; nf < 4; ++nf)
                    acc[mf][nf] = __builtin_amdgcn_mfma_f32_16x16x32_bf16(
                        af[mf], bf[nf], acc[mf][nf], 0, 0, 0);
            __builtin_amdgcn_s_setprio(0);
        }
        asm volatile("s_waitcnt vmcnt(0) lgkmcnt(0)" ::: "memory");
        __builtin_amdgcn_s_barrier();
        __builtin_amdgcn_sched_barrier(0);
        cur ^= 1;
    }

    if constexpr (ROPE) {
        if (n0 < 2048) {   // block-uniform: Q/K columns only
#pragma unroll
            for (int mf = 0; mf < 4; ++mf)
#pragma unroll
                for (int nf = 0; nf < 4; ++nf) {
                    const int ii = (nf * 16 + l16) >> 1;
                    const float sgn = (l16 & 1) ? 1.0f : -1.0f;
#pragma unroll
                    for (int rr = 0; rr < 4; ++rr) {
                        int row = m0 + wm * 64 + mf * 16 + lq * 4 + rr;
                        float v = acc[mf][nf][rr];
                        float p = __shfl_xor(v, 1);
                        float2 cs = tab[(row & (T_ - 1)) * 32 + ii];
                        acc[mf][nf][rr] = v * cs.x + sgn * (p * cs.y);
                    }
                }
        }
    }
#pragma unroll
    for (int mf = 0; mf < 4; ++mf)
#pragma unroll
        for (int nf = 0; nf < 4; ++nf)
#pragma unroll
            for (int rr = 0; rr < 4; ++rr) {
                int row = m0 + wm * 64 + mf * 16 + lq * 4 + rr;
                int col = n0 + wn * 64 + nf * 16 + l16;
                if constexpr (CF32)
                    ((float*)Cp)[(size_t)row * N + col] = acc[mf][nf][rr];
                else
                    ((short*)Cp)[(size_t)row * N + col] = f2b(acc[mf][nf][rr]);
            }
}

// V region of qkv -> vT[(b*16+h)*64 + d][t]  (per-(b,h) 64 x 2048, bf16)
__global__ __launch_bounds__(256) void transpose_v(const short* __restrict__ qkv,
                                                   short* __restrict__ vT) {
    const int blk = blockIdx.x;
    const int bh = blk >> 5, tt = blk & 31;
    const int b = bh >> 4, h = bh & 15;
    const int t0 = tt * 64;
    const int tid = threadIdx.x;
    __shared__ int tile[64][65];
#pragma unroll
    for (int p = 0; p < 2; ++p) {
        int c = p * 256 + tid;
        int t = c >> 3, d0 = (c & 7) * 8;
        short8 v = *(const short8*)(qkv + (size_t)(b * T_ + t0 + t) * NQKV + 2 * C_ + h * 64 + d0);
#pragma unroll
        for (int u = 0; u < 8; ++u) tile[t][d0 + u] = v[u];
    }
    __syncthreads();
#pragma unroll
    for (int p = 0; p < 2; ++p) {
        int c = p * 256 + tid;
        int d = c >> 3, tq0 = (c & 7) * 8;
        short8 s;
#pragma unroll
        for (int u = 0; u < 8; ++u) s[u] = (short)tile[tq0 + u][d];
        *(short8*)(vT + (size_t)(bh * 64 + d) * 2048 + t0 + tq0) = s;
    }
}

// MFMA flash attention: block = (b,h,128 q rows), 4 waves, each wave 2 groups of 16 rows.
__global__ __launch_bounds__(256) void attn_mfma(const short* __restrict__ qkv,
                                                 const short* __restrict__ vT,
                                                 short* __restrict__ att) {
    const int blk = blockIdx.x;
    const int bh = blk & 63;               // all heads of a qt dispatch together
    const int qt = 15 - (blk >> 6);        // heavy q-tiles first
    const int b = bh >> 4, h = bh & 15;
    const int q0 = qt * 128;
    const int tid = threadIdx.x;
    const int w = tid >> 6, l = tid & 63;
    const int l16 = l & 15, lq = l >> 4;
    const int e = l16 & 7;                 // row-XOR term for fragment reads

    __shared__ short Ks[64 * 64];
    __shared__ short Vs[64 * 64];
    __shared__ short Ps[4][16 * 64];

    short8 qf[2][2];
#pragma unroll
    for (int rg = 0; rg < 2; ++rg) {
        const size_t qrow = (size_t)((b * T_) + q0 + rg * 64 + w * 16 + l16) * NQKV + h * 64;
#pragma unroll
        for (int kk = 0; kk < 2; ++kk) {
            short8 raw = *(const short8*)(qkv + qrow + kk * 32 + lq * 8);
            short8 s;
#pragma unroll
            for (int j = 0; j < 8; ++j) s[j] = f2b(0.125f * b2f(raw[j]));
            qf[rg][kk] = s;
        }
    }
    f32x4 acc[2][4];
#pragma unroll
    for (int rg = 0; rg < 2; ++rg)
#pragma unroll
        for (int dt = 0; dt < 4; ++dt) acc[rg][dt] = fz4();
    float m_s[2] = {-1e30f, -1e30f}, l_s[2] = {0.f, 0.f};

    const int nt = 2 * qt + 2;
    for (int t = 0; t < nt; ++t) {
        const int k0 = t * 64;
        {   // stage K from qkv, V from vT; linear LDS dest, swizzled global chunk
            const size_t kbase = (size_t)((b * T_) + k0) * NQKV + C_ + h * 64;
            const size_t vbase = (size_t)(bh * 64) * 2048 + k0;
#pragma unroll
            for (int p = 0; p < 2; ++p) {
                int c = p * 256 + tid;
                int r = c >> 3;
                int cg = (c & 7) ^ (r & 7);
                load_lds16(qkv + kbase + (size_t)r * NQKV + cg * 8,
                           &Ks[p * 2048 + (tid & ~63) * 8]);
                load_lds16(vT + vbase + (size_t)r * 2048 + cg * 8,
                           &Vs[p * 2048 + (tid & ~63) * 8]);
            }
        }
        __syncthreads();
#pragma unroll
        for (int rg = 0; rg < 2; ++rg) {
            if (rg == 0 && t == nt - 1) continue;   // block-uniform skip
            const int qg = q0 + rg * 64 + w * 16 + l16;
            f32x4 sc[4];
#pragma unroll
            for (int ct = 0; ct < 4; ++ct) sc[ct] = fz4();
            __builtin_amdgcn_s_setprio(1);
#pragma unroll
            for (int kk = 0; kk < 2; ++kk)
#pragma unroll
                for (int ct = 0; ct < 4; ++ct) {
                    short8 ak = *(const short8*)&Ks[(ct * 16 + l16) * 64 + (((kk * 4 + lq) ^ e) * 8)];
                    sc[ct] = __builtin_amdgcn_mfma_f32_16x16x32_bf16(ak, qf[rg][kk], sc[ct], 0, 0, 0);
                }
            __builtin_amdgcn_s_setprio(0);
            if (k0 + 63 > q0 + rg * 64 + w * 16) {
#pragma unroll
                for (int ct = 0; ct < 4; ++ct)
#pragma unroll
                    for (int r = 0; r < 4; ++r)
                        if (k0 + ct * 16 + lq * 4 + r > qg) sc[ct][r] = -1e30f;
            }
            float mx = -1e30f;
#pragma unroll
            for (int ct = 0; ct < 4; ++ct)
#pragma unroll
                for (int r = 0; r < 4; ++r) mx = fmaxf(mx, sc[ct][r]);
            mx = fmaxf(mx, __shfl_xor(mx, 16));
            mx = fmaxf(mx, __shfl_xor(mx, 32));
            float mn = fmaxf(m_s[rg], mx);
            float al = __expf(m_s[rg] - mn);
            m_s[rg] = mn;
            float s0 = 0.f;
#pragma unroll
            for (int ct = 0; ct < 4; ++ct)
#pragma unroll
                for (int r = 0; r < 4; ++r) {
                    float p = __expf(sc[ct][r] - mn);
                    sc[ct][r] = p;
                    s0 += p;
                }
            s0 += __shfl_xor(s0, 16);
            s0 += __shfl_xor(s0, 32);
            l_s[rg] = l_s[rg] * al + s0;
            float albc[4];
#pragma unroll
            for (int r = 0; r < 4; ++r) albc[r] = __shfl(al, lq * 4 + r);
#pragma unroll
            for (int dt = 0; dt < 4; ++dt) {
                f32x4 a4 = acc[rg][dt];
                a4[0] *= albc[0]; a4[1] *= albc[1]; a4[2] *= albc[2]; a4[3] *= albc[3];
                acc[rg][dt] = a4;
            }
#pragma unroll
            for (int ct = 0; ct < 4; ++ct)
#pragma unroll
                for (int r = 0; r < 4; ++r) {
                    int k = ct * 16 + lq * 4 + r;
                    Ps[w][l16 * 64 + (((k >> 3) ^ e) * 8) + (k & 7)] = f2b(sc[ct][r]);
                }
            __builtin_amdgcn_s_setprio(1);
#pragma unroll
            for (int kk = 0; kk < 2; ++kk) {
                short8 pa = *(const short8*)&Ps[w][l16 * 64 + (((kk * 4 + lq) ^ e) * 8)];
#pragma unroll
                for (int dt = 0; dt < 4; ++dt) {
                    short8 bv = *(const short8*)&Vs[(dt * 16 + l16) * 64 + (((kk * 4 + lq) ^ e) * 8)];
                    acc[rg][dt] = __builtin_amdgcn_mfma_f32_16x16x32_bf16(pa, bv, acc[rg][dt], 0, 0, 0);
                }
            }
            __builtin_amdgcn_s_setprio(0);
        }
        __syncthreads();
    }
#pragma unroll
    for (int rg = 0; rg < 2; ++rg) {
        float lbc[4];
#pragma unroll
        for (int r = 0; r < 4; ++r) lbc[r] = __shfl(l_s[rg], lq * 4 + r);
#pragma unroll
        for (int r = 0; r < 4; ++r) {
            float inv = 1.0f / lbc[r];
            size_t ob = (size_t)((b * T_) + q0 + rg * 64 + w * 16 + lq * 4 + r) * C_ + h * 64 + l16;
#pragma unroll
            for (int dt = 0; dt < 4; ++dt)
                att[ob + dt * 16] = f2b(acc[rg][dt][r] * inv);
        }
    }
}

extern "C" void kernel_launch(void* const* d_in, const int* in_sizes, int n_in,
                              void* d_out, int out_size, void* d_ws, size_t ws_size,
                              hipStream_t stream) {
    const float* x = (const float*)d_in[0];
    const float* Wqkv = (const float*)d_in[1];
    const float* Wproj = (const float*)d_in[2];
    float* out = (float*)d_out;
    char* ws = (char*)d_ws;

    short* qkv = (short*)ws;                                     // [0, 48MB)
    short* att = (short*)(ws + (size_t)BT_ * NQKV * 2);          // [48MB, 64MB)
    short* wqb = att;                                            // 6MB, dead before att written
    float2* tab = (float2*)(ws + (size_t)BT_ * NQKV * 2 + (size_t)3 * C_ * C_ * 2); // 512KB @ 54MB
    short* wpb = qkv;                                            // 2MB, qkv dead by then
    short* vT  = (short*)d_out;                                  // 16MB scratch until final GEMM

    // 1) rope table + Wqkv -> bf16
    rope_table<<<256, 256, 0, stream>>>(tab);
    cvt_kernel<<<(3 * C_ * C_) / 2048, 256, 0, stream>>>(Wqkv, wqb, 3 * C_ * C_);
    // 2) qkv = x @ Wqkv^T with fused RoPE (bf16 out)
    dim3 g1(BT_ / 128, NQKV / 128);
    gemm_mfma<1, 0, 1><<<g1, 256, 0, stream>>>((const void*)x, wqb, (void*)qkv, BT_, NQKV, C_, tab);
    // 3) V -> vT (per-(b,h) transpose)
    transpose_v<<<64 * 32, 256, 0, stream>>>(qkv, vT);
    // 4) attention
    attn_mfma<<<B_ * H_ * (T_ / 128), 256, 0, stream>>>(qkv, vT, att);
    // 5) Wproj -> bf16
    cvt_kernel<<<(C_ * C_) / 2048, 256, 0, stream>>>(Wproj, wpb, C_ * C_);
    // 6) out = att @ Wproj^T (fp32 out)
    dim3 g2(BT_ / 128, C_ / 128);
    gemm_mfma<0, 1, 0><<<g2, 256, 0, stream>>>((const void*)att, wpb, (void*)out, BT_, C_, C_, tab);
}

// Round 7
// 215.803 us; speedup vs baseline: 24.7835x; 1.0046x over previous
//
#include <hip/hip_runtime.h>
#include <hip/hip_bf16.h>

#define B_   4
#define T_   2048
#define C_   1024
#define H_   16
#define BT_  (B_ * T_)      // 8192
#define NQKV (3 * C_)       // 3072

typedef __attribute__((ext_vector_type(8))) short short8;
typedef __attribute__((ext_vector_type(4))) float f32x4;

__device__ inline float b2f(short u) {
    unsigned int x = ((unsigned int)(unsigned short)u) << 16;
    float f;
    __builtin_memcpy(&f, &x, 4);
    return f;
}
__device__ inline short f2b(float f) {
    __hip_bfloat16 h = __float2bfloat16(f);
    unsigned short u;
    __builtin_memcpy(&u, &h, 2);
    return (short)u;
}
__device__ inline f32x4 fz4() { f32x4 z; z[0] = z[1] = z[2] = z[3] = 0.f; return z; }

__device__ inline void load_lds16(const void* g, void* l) {
    __builtin_amdgcn_global_load_lds((const __attribute__((address_space(1))) unsigned int*)g,
                                     (__attribute__((address_space(3))) unsigned int*)l,
                                     16, 0, 0);
}

// fp32 -> bf16 bulk convert (n multiple of 2048)
__global__ __launch_bounds__(256) void cvt_kernel(const float* __restrict__ in,
                                                  short* __restrict__ out, int n) {
    int i = (blockIdx.x * 256 + threadIdx.x) * 8;
    if (i >= n) return;
    float4 a = *(const float4*)(in + i);
    float4 b = *(const float4*)(in + i + 4);
    short8 s;
    s[0] = f2b(a.x); s[1] = f2b(a.y); s[2] = f2b(a.z); s[3] = f2b(a.w);
    s[4] = f2b(b.x); s[5] = f2b(b.y); s[6] = f2b(b.z); s[7] = f2b(b.w);
    *(short8*)(out + i) = s;
}

// cos/sin table: tab[t*32+i] = (cos, sin) of t * 10000^(-i/32), t<2048, i<32
__global__ __launch_bounds__(256) void rope_table(float2* __restrict__ tab) {
    int idx = blockIdx.x * 256 + threadIdx.x;   // 65536
    int t = idx >> 5, i = idx & 31;
    float inv = exp2f(-(float)i * 0.41524101186092029f);
    float ang = (float)t * inv;
    float s, c;
    sincosf(ang, &s, &c);
    tab[idx] = make_float2(c, s);
}

// C[m][n] = sum_k A[m][k] * Bw[n][k]; A,Bw bf16 [.][K]. 128x128 tile, BK=64, 4 waves.
// m97 structure: single-buffer linear LDS, global_load_lds width 16, 2-barrier K loop.
// ROPE: fused rotary on fp32 acc for cols < 2048 (pair exchange via shfl_xor 1).
template <int CF32, int ROPE>
__global__ __launch_bounds__(256) void gemm_mfma(const short* __restrict__ Ab,
                                                 const short* __restrict__ Bw,
                                                 void* __restrict__ Cp,
                                                 int M, int N, int K,
                                                 const float2* __restrict__ tab) {
    __shared__ short As[128 * 64];
    __shared__ short Bs[128 * 64];
    const int tid = threadIdx.x;
    const int l16 = tid & 15, lq = (tid & 63) >> 4;
    const int wid = tid >> 6;
    const int wm = wid >> 1, wn = wid & 1;
    const int m0 = blockIdx.x * 128, n0 = blockIdx.y * 128;

    f32x4 acc[4][4];
#pragma unroll
    for (int i = 0; i < 4; ++i)
#pragma unroll
        for (int j = 0; j < 4; ++j) acc[i][j] = fz4();

    for (int k0 = 0; k0 < K; k0 += 64) {
#pragma unroll
        for (int i = 0; i < 4; ++i) {
            int c = i * 256 + tid;
            int r = c >> 3, col = c & 7;
            load_lds16(Bw + (size_t)(n0 + r) * K + k0 + col * 8,
                       &Bs[i * 2048 + (tid & ~63) * 8]);
            load_lds16(Ab + (size_t)(m0 + r) * K + k0 + col * 8,
                       &As[i * 2048 + (tid & ~63) * 8]);
        }
        __syncthreads();
#pragma unroll
        for (int kk = 0; kk < 2; ++kk) {
            short8 af[4], bf[4];
#pragma unroll
            for (int mf = 0; mf < 4; ++mf)
                af[mf] = *(const short8*)&As[(wm * 64 + mf * 16 + l16) * 64 + (kk * 4 + lq) * 8];
#pragma unroll
            for (int nf = 0; nf < 4; ++nf)
                bf[nf] = *(const short8*)&Bs[(wn * 64 + nf * 16 + l16) * 64 + (kk * 4 + lq) * 8];
#pragma unroll
            for (int mf = 0; mf < 4; ++mf)
#pragma unroll
                for (int nf = 0; nf < 4; ++nf)
                    acc[mf][nf] = __builtin_amdgcn_mfma_f32_16x16x32_bf16(
                        af[mf], bf[nf], acc[mf][nf], 0, 0, 0);
        }
        __syncthreads();
    }

    if constexpr (ROPE) {
        if (n0 < 2048) {   // block-uniform: Q/K columns only
#pragma unroll
            for (int mf = 0; mf < 4; ++mf)
#pragma unroll
                for (int nf = 0; nf < 4; ++nf) {
                    const int ii = (nf * 16 + l16) >> 1;
                    const float sgn = (l16 & 1) ? 1.0f : -1.0f;
#pragma unroll
                    for (int rr = 0; rr < 4; ++rr) {
                        int row = m0 + wm * 64 + mf * 16 + lq * 4 + rr;
                        float v = acc[mf][nf][rr];
                        float p = __shfl_xor(v, 1);
                        float2 cs = tab[(row & (T_ - 1)) * 32 + ii];
                        acc[mf][nf][rr] = v * cs.x + sgn * (p * cs.y);
                    }
                }
        }
    }
#pragma unroll
    for (int mf = 0; mf < 4; ++mf)
#pragma unroll
        for (int nf = 0; nf < 4; ++nf)
#pragma unroll
            for (int rr = 0; rr < 4; ++rr) {
                int row = m0 + wm * 64 + mf * 16 + lq * 4 + rr;
                int col = n0 + wn * 64 + nf * 16 + l16;
                if constexpr (CF32)
                    ((float*)Cp)[(size_t)row * N + col] = acc[mf][nf][rr];
                else
                    ((short*)Cp)[(size_t)row * N + col] = f2b(acc[mf][nf][rr]);
            }
}

// V region of qkv -> vT[(b*16+h)*64 + d][t]  (per-(b,h) 64 x 2048, bf16)
__global__ __launch_bounds__(256) void transpose_v(const short* __restrict__ qkv,
                                                   short* __restrict__ vT) {
    const int blk = blockIdx.x;
    const int bh = blk >> 5, tt = blk & 31;
    const int b = bh >> 4, h = bh & 15;
    const int t0 = tt * 64;
    const int tid = threadIdx.x;
    __shared__ int tile[64][65];
#pragma unroll
    for (int p = 0; p < 2; ++p) {
        int c = p * 256 + tid;
        int t = c >> 3, d0 = (c & 7) * 8;
        short8 v = *(const short8*)(qkv + (size_t)(b * T_ + t0 + t) * NQKV + 2 * C_ + h * 64 + d0);
#pragma unroll
        for (int u = 0; u < 8; ++u) tile[t][d0 + u] = v[u];
    }
    __syncthreads();
#pragma unroll
    for (int p = 0; p < 2; ++p) {
        int c = p * 256 + tid;
        int d = c >> 3, tq0 = (c & 7) * 8;
        short8 s;
#pragma unroll
        for (int u = 0; u < 8; ++u) s[u] = (short)tile[tq0 + u][d];
        *(short8*)(vT + (size_t)(bh * 64 + d) * 2048 + t0 + tq0) = s;
    }
}

// MFMA flash attention: block = (b,h,128 q rows), 4 waves, each wave 2 groups of 16 rows.
__global__ __launch_bounds__(256) void attn_mfma(const short* __restrict__ qkv,
                                                 const short* __restrict__ vT,
                                                 short* __restrict__ att) {
    const int blk = blockIdx.x;
    const int bh = blk & 63;               // all heads of a qt dispatch together
    const int qt = 15 - (blk >> 6);        // heavy q-tiles first
    const int b = bh >> 4, h = bh & 15;
    const int q0 = qt * 128;
    const int tid = threadIdx.x;
    const int w = tid >> 6, l = tid & 63;
    const int l16 = l & 15, lq = l >> 4;
    const int e = l16 & 7;                 // row-XOR term for fragment reads

    __shared__ short Ks[64 * 64];
    __shared__ short Vs[64 * 64];
    __shared__ short Ps[4][16 * 64];

    short8 qf[2][2];
#pragma unroll
    for (int rg = 0; rg < 2; ++rg) {
        const size_t qrow = (size_t)((b * T_) + q0 + rg * 64 + w * 16 + l16) * NQKV + h * 64;
#pragma unroll
        for (int kk = 0; kk < 2; ++kk) {
            short8 raw = *(const short8*)(qkv + qrow + kk * 32 + lq * 8);
            short8 s;
#pragma unroll
            for (int j = 0; j < 8; ++j) s[j] = f2b(0.125f * b2f(raw[j]));
            qf[rg][kk] = s;
        }
    }
    f32x4 acc[2][4];
#pragma unroll
    for (int rg = 0; rg < 2; ++rg)
#pragma unroll
        for (int dt = 0; dt < 4; ++dt) acc[rg][dt] = fz4();
    float m_s[2] = {-1e30f, -1e30f}, l_s[2] = {0.f, 0.f};

    const int nt = 2 * qt + 2;
    for (int t = 0; t < nt; ++t) {
        const int k0 = t * 64;
        {   // stage K from qkv, V from vT; linear LDS dest, swizzled global chunk
            const size_t kbase = (size_t)((b * T_) + k0) * NQKV + C_ + h * 64;
            const size_t vbase = (size_t)(bh * 64) * 2048 + k0;
#pragma unroll
            for (int p = 0; p < 2; ++p) {
                int c = p * 256 + tid;
                int r = c >> 3;
                int cg = (c & 7) ^ (r & 7);
                load_lds16(qkv + kbase + (size_t)r * NQKV + cg * 8,
                           &Ks[p * 2048 + (tid & ~63) * 8]);
                load_lds16(vT + vbase + (size_t)r * 2048 + cg * 8,
                           &Vs[p * 2048 + (tid & ~63) * 8]);
            }
        }
        __syncthreads();
#pragma unroll
        for (int rg = 0; rg < 2; ++rg) {
            if (rg == 0 && t == nt - 1) continue;   // block-uniform skip
            const int qg = q0 + rg * 64 + w * 16 + l16;
            f32x4 sc[4];
#pragma unroll
            for (int ct = 0; ct < 4; ++ct) sc[ct] = fz4();
            __builtin_amdgcn_s_setprio(1);
#pragma unroll
            for (int kk = 0; kk < 2; ++kk)
#pragma unroll
                for (int ct = 0; ct < 4; ++ct) {
                    short8 ak = *(const short8*)&Ks[(ct * 16 + l16) * 64 + (((kk * 4 + lq) ^ e) * 8)];
                    sc[ct] = __builtin_amdgcn_mfma_f32_16x16x32_bf16(ak, qf[rg][kk], sc[ct], 0, 0, 0);
                }
            __builtin_amdgcn_s_setprio(0);
            if (k0 + 63 > q0 + rg * 64 + w * 16) {
#pragma unroll
                for (int ct = 0; ct < 4; ++ct)
#pragma unroll
                    for (int r = 0; r < 4; ++r)
                        if (k0 + ct * 16 + lq * 4 + r > qg) sc[ct][r] = -1e30f;
            }
            float mx = -1e30f;
#pragma unroll
            for (int ct = 0; ct < 4; ++ct)
#pragma unroll
                for (int r = 0; r < 4; ++r) mx = fmaxf(mx, sc[ct][r]);
            mx = fmaxf(mx, __shfl_xor(mx, 16));
            mx = fmaxf(mx, __shfl_xor(mx, 32));
            float mn = fmaxf(m_s[rg], mx);
            float al = __expf(m_s[rg] - mn);
            m_s[rg] = mn;
            float s0 = 0.f;
#pragma unroll
            for (int ct = 0; ct < 4; ++ct)
#pragma unroll
                for (int r = 0; r < 4; ++r) {
                    float p = __expf(sc[ct][r] - mn);
                    sc[ct][r] = p;
                    s0 += p;
                }
            s0 += __shfl_xor(s0, 16);
            s0 += __shfl_xor(s0, 32);
            l_s[rg] = l_s[rg] * al + s0;
            float albc[4];
#pragma unroll
            for (int r = 0; r < 4; ++r) albc[r] = __shfl(al, lq * 4 + r);
#pragma unroll
            for (int dt = 0; dt < 4; ++dt) {
                f32x4 a4 = acc[rg][dt];
                a4[0] *= albc[0]; a4[1] *= albc[1]; a4[2] *= albc[2]; a4[3] *= albc[3];
                acc[rg][dt] = a4;
            }
#pragma unroll
            for (int ct = 0; ct < 4; ++ct)
#pragma unroll
                for (int r = 0; r < 4; ++r) {
                    int k = ct * 16 + lq * 4 + r;
                    Ps[w][l16 * 64 + (((k >> 3) ^ e) * 8) + (k & 7)] = f2b(sc[ct][r]);
                }
            __builtin_amdgcn_s_setprio(1);
#pragma unroll
            for (int kk = 0; kk < 2; ++kk) {
                short8 pa = *(const short8*)&Ps[w][l16 * 64 + (((kk * 4 + lq) ^ e) * 8)];
#pragma unroll
                for (int dt = 0; dt < 4; ++dt) {
                    short8 bv = *(const short8*)&Vs[(dt * 16 + l16) * 64 + (((kk * 4 + lq) ^ e) * 8)];
                    acc[rg][dt] = __builtin_amdgcn_mfma_f32_16x16x32_bf16(pa, bv, acc[rg][dt], 0, 0, 0);
                }
            }
            __builtin_amdgcn_s_setprio(0);
        }
        __syncthreads();
    }
#pragma unroll
    for (int rg = 0; rg < 2; ++rg) {
        float lbc[4];
#pragma unroll
        for (int r = 0; r < 4; ++r) lbc[r] = __shfl(l_s[rg], lq * 4 + r);
#pragma unroll
        for (int r = 0; r < 4; ++r) {
            float inv = 1.0f / lbc[r];
            size_t ob = (size_t)((b * T_) + q0 + rg * 64 + w * 16 + lq * 4 + r) * C_ + h * 64 + l16;
#pragma unroll
            for (int dt = 0; dt < 4; ++dt)
                att[ob + dt * 16] = f2b(acc[rg][dt][r] * inv);
        }
    }
}

extern "C" void kernel_launch(void* const* d_in, const int* in_sizes, int n_in,
                              void* d_out, int out_size, void* d_ws, size_t ws_size,
                              hipStream_t stream) {
    const float* x = (const float*)d_in[0];
    const float* Wqkv = (const float*)d_in[1];
    const float* Wproj = (const float*)d_in[2];
    char* ws = (char*)d_ws;

    short* qkv = (short*)ws;                                     // [0, 48MB)
    short* att = (short*)(ws + (size_t)BT_ * NQKV * 2);          // [48MB, 64MB)
    short* wqb = att;                                            // 6MB, dead before att written
    float2* tab = (float2*)(ws + (size_t)BT_ * NQKV * 2 + (size_t)3 * C_ * C_ * 2); // 512KB @ 54MB
    short* wpb = qkv;                                            // 2MB, qkv dead by then
    short* vT  = (short*)d_out;                                  // d_out[0,16MB): V^T scratch
    short* xb  = (short*)((char*)d_out + ((size_t)BT_ * C_ * 2)); // d_out[16,32MB): x bf16

    // 1) rope table + x,Wqkv -> bf16
    rope_table<<<256, 256, 0, stream>>>(tab);
    cvt_kernel<<<(BT_ * C_) / 2048, 256, 0, stream>>>(x, xb, BT_ * C_);
    cvt_kernel<<<(3 * C_ * C_) / 2048, 256, 0, stream>>>(Wqkv, wqb, 3 * C_ * C_);
    // 2) qkv = xb @ Wqkv^T with fused RoPE (bf16 out)
    dim3 g1(BT_ / 128, NQKV / 128);
    gemm_mfma<0, 1><<<g1, 256, 0, stream>>>(xb, wqb, (void*)qkv, BT_, NQKV, C_, tab);
    // 3) V -> vT (per-(b,h) transpose)
    transpose_v<<<64 * 32, 256, 0, stream>>>(qkv, vT);
    // 4) attention
    attn_mfma<<<B_ * H_ * (T_ / 128), 256, 0, stream>>>(qkv, vT, att);
    // 5) Wproj -> bf16
    cvt_kernel<<<(C_ * C_) / 2048, 256, 0, stream>>>(Wproj, wpb, C_ * C_);
    // 6) out = att @ Wproj^T (fp32 out; overwrites vT/xb scratch)
    dim3 g2(BT_ / 128, C_ / 128);
    gemm_mfma<1, 0><<<g2, 256, 0, stream>>>(att, wpb, d_out, BT_, C_, C_, tab);
}

// Round 8
// 206.922 us; speedup vs baseline: 25.8473x; 1.0429x over previous
//
#include <hip/hip_runtime.h>
#include <hip/hip_bf16.h>

#define B_   4
#define T_   2048
#define C_   1024
#define H_   16
#define BT_  (B_ * T_)      // 8192
#define NQKV (3 * C_)       // 3072

typedef __attribute__((ext_vector_type(8))) short short8;
typedef __attribute__((ext_vector_type(4))) float f32x4;

__device__ inline float b2f(short u) {
    unsigned int x = ((unsigned int)(unsigned short)u) << 16;
    float f;
    __builtin_memcpy(&f, &x, 4);
    return f;
}
__device__ inline short f2b(float f) {
    __hip_bfloat16 h = __float2bfloat16(f);
    unsigned short u;
    __builtin_memcpy(&u, &h, 2);
    return (short)u;
}
__device__ inline f32x4 fz4() { f32x4 z; z[0] = z[1] = z[2] = z[3] = 0.f; return z; }

__device__ inline void load_lds16(const void* g, void* l) {
    __builtin_amdgcn_global_load_lds((const __attribute__((address_space(1))) unsigned int*)g,
                                     (__attribute__((address_space(3))) unsigned int*)l,
                                     16, 0, 0);
}
__device__ inline void barrier_nodrain() {
    __builtin_amdgcn_sched_barrier(0);
    __builtin_amdgcn_s_barrier();
    __builtin_amdgcn_sched_barrier(0);
}

// fp32 -> bf16 bulk convert (n multiple of 2048)
__global__ __launch_bounds__(256) void cvt_kernel(const float* __restrict__ in,
                                                  short* __restrict__ out, int n) {
    int i = (blockIdx.x * 256 + threadIdx.x) * 8;
    if (i >= n) return;
    float4 a = *(const float4*)(in + i);
    float4 b = *(const float4*)(in + i + 4);
    short8 s;
    s[0] = f2b(a.x); s[1] = f2b(a.y); s[2] = f2b(a.z); s[3] = f2b(a.w);
    s[4] = f2b(b.x); s[5] = f2b(b.y); s[6] = f2b(b.z); s[7] = f2b(b.w);
    *(short8*)(out + i) = s;
}

// cos/sin table: tab[t*32+i] = (cos, sin) of t * 10000^(-i/32), t<2048, i<32
__global__ __launch_bounds__(256) void rope_table(float2* __restrict__ tab) {
    int idx = blockIdx.x * 256 + threadIdx.x;   // 65536
    int t = idx >> 5, i = idx & 31;
    float inv = exp2f(-(float)i * 0.41524101186092029f);
    float ang = (float)t * inv;
    float s, c;
    sincosf(ang, &s, &c);
    tab[idx] = make_float2(c, s);
}

// C[m][n] = sum_k A[m][k]*Bw[n][k]; A,Bw bf16 [.][K]. 128x256 tile, BK=64, 8 waves.
// Ring-2 LDS, counted vmcnt(6) across raw barriers (T3-min+T4), chunk-XOR swizzle.
template <int CF32, int ROPE>
__global__ __launch_bounds__(512) void gemm_pipe(const short* __restrict__ Ab,
                                                 const short* __restrict__ Bw,
                                                 void* __restrict__ Cp,
                                                 int M, int N, int K,
                                                 const float2* __restrict__ tab) {
    __shared__ short As[2][128 * 64];
    __shared__ short Bs[2][256 * 64];
    const int tid = threadIdx.x;
    const int l16 = tid & 15, lq = (tid & 63) >> 4;
    const int wid = tid >> 6;          // 0..7
    const int wm = wid >> 2, wn = wid & 3;   // 2M x 4N wave grid
    const int m0 = blockIdx.x * 128, n0 = blockIdx.y * 256;
    const int NT = K >> 6;

    f32x4 acc[4][4];
#pragma unroll
    for (int i = 0; i < 4; ++i)
#pragma unroll
        for (int j = 0; j < 4; ++j) acc[i][j] = fz4();

    auto stage = [&](int bf, int t) {   // 6 gload_lds per thread
        const int k0 = t * 64;
#pragma unroll
        for (int p = 0; p < 2; ++p) {
            int c = p * 512 + tid;
            int r = c >> 3, cs = (c & 7) ^ (r & 7);
            load_lds16(Ab + (size_t)(m0 + r) * K + k0 + cs * 8,
                       &As[bf][(p * 512 + (tid & ~63)) * 8]);
        }
#pragma unroll
        for (int p = 0; p < 4; ++p) {
            int c = p * 512 + tid;
            int r = c >> 3, cs = (c & 7) ^ (r & 7);
            load_lds16(Bw + (size_t)(n0 + r) * K + k0 + cs * 8,
                       &Bs[bf][(p * 512 + (tid & ~63)) * 8]);
        }
    };

    stage(0, 0);
    for (int t = 0; t < NT; ++t) {
        if (t + 1 < NT) {
            stage((t + 1) & 1, t + 1);
            asm volatile("s_waitcnt vmcnt(6)" ::: "memory");   // tile t landed; t+1 in flight
        } else {
            asm volatile("s_waitcnt vmcnt(0)" ::: "memory");
        }
        barrier_nodrain();
        const short* Ac = As[t & 1];
        const short* Bc = Bs[t & 1];
#pragma unroll
        for (int kk = 0; kk < 2; ++kk) {
            short8 af[4], bfr[4];
#pragma unroll
            for (int mf = 0; mf < 4; ++mf) {
                int row = wm * 64 + mf * 16 + l16;
                af[mf] = *(const short8*)&Ac[row * 64 + (((kk * 4 + lq) ^ (row & 7)) * 8)];
            }
#pragma unroll
            for (int nf = 0; nf < 4; ++nf) {
                int row = wn * 64 + nf * 16 + l16;
                bfr[nf] = *(const short8*)&Bc[row * 64 + (((kk * 4 + lq) ^ (row & 7)) * 8)];
            }
            __builtin_amdgcn_s_setprio(1);
#pragma unroll
            for (int mf = 0; mf < 4; ++mf)
#pragma unroll
                for (int nf = 0; nf < 4; ++nf)
                    acc[mf][nf] = __builtin_amdgcn_mfma_f32_16x16x32_bf16(
                        af[mf], bfr[nf], acc[mf][nf], 0, 0, 0);
            __builtin_amdgcn_s_setprio(0);
        }
        barrier_nodrain();   // readers done before next stage overwrites
    }

    if constexpr (ROPE) {
        if (n0 < 2048) {   // block-uniform: Q/K columns only
#pragma unroll
            for (int mf = 0; mf < 4; ++mf)
#pragma unroll
                for (int nf = 0; nf < 4; ++nf) {
                    const int ii = (nf * 16 + l16) >> 1;
                    const float sgn = (l16 & 1) ? 1.0f : -1.0f;
#pragma unroll
                    for (int rr = 0; rr < 4; ++rr) {
                        int row = m0 + wm * 64 + mf * 16 + lq * 4 + rr;
                        float v = acc[mf][nf][rr];
                        float p = __shfl_xor(v, 1);
                        float2 cs = tab[(row & (T_ - 1)) * 32 + ii];
                        acc[mf][nf][rr] = v * cs.x + sgn * (p * cs.y);
                    }
                }
        }
    }
#pragma unroll
    for (int mf = 0; mf < 4; ++mf)
#pragma unroll
        for (int nf = 0; nf < 4; ++nf)
#pragma unroll
            for (int rr = 0; rr < 4; ++rr) {
                int row = m0 + wm * 64 + mf * 16 + lq * 4 + rr;
                int col = n0 + wn * 64 + nf * 16 + l16;
                if constexpr (CF32)
                    ((float*)Cp)[(size_t)row * N + col] = acc[mf][nf][rr];
                else
                    ((short*)Cp)[(size_t)row * N + col] = f2b(acc[mf][nf][rr]);
            }
}

// V region of qkv -> vT[(b*16+h)*64 + d][t]  (per-(b,h) 64 x 2048, bf16)
__global__ __launch_bounds__(256) void transpose_v(const short* __restrict__ qkv,
                                                   short* __restrict__ vT) {
    const int blk = blockIdx.x;
    const int bh = blk >> 5, tt = blk & 31;
    const int b = bh >> 4, h = bh & 15;
    const int t0 = tt * 64;
    const int tid = threadIdx.x;
    __shared__ int tile[64][65];
#pragma unroll
    for (int p = 0; p < 2; ++p) {
        int c = p * 256 + tid;
        int t = c >> 3, d0 = (c & 7) * 8;
        short8 v = *(const short8*)(qkv + (size_t)(b * T_ + t0 + t) * NQKV + 2 * C_ + h * 64 + d0);
#pragma unroll
        for (int u = 0; u < 8; ++u) tile[t][d0 + u] = v[u];
    }
    __syncthreads();
#pragma unroll
    for (int p = 0; p < 2; ++p) {
        int c = p * 256 + tid;
        int d = c >> 3, tq0 = (c & 7) * 8;
        short8 s;
#pragma unroll
        for (int u = 0; u < 8; ++u) s[u] = (short)tile[tq0 + u][d];
        *(short8*)(vT + (size_t)(bh * 64 + d) * 2048 + t0 + tq0) = s;
    }
}

// MFMA flash attention: block = (b,h,128 q rows), 4 waves x 2 row-groups.
// Ring-2 K/V with counted vmcnt(4) across raw barriers.
__global__ __launch_bounds__(256) void attn_mfma(const short* __restrict__ qkv,
                                                 const short* __restrict__ vT,
                                                 short* __restrict__ att) {
    const int blk = blockIdx.x;
    const int bh = blk & 63;               // all heads of a qt dispatch together
    const int qt = 15 - (blk >> 6);        // heavy q-tiles first
    const int b = bh >> 4, h = bh & 15;
    const int q0 = qt * 128;
    const int tid = threadIdx.x;
    const int w = tid >> 6, l = tid & 63;
    const int l16 = l & 15, lq = l >> 4;
    const int e = l16 & 7;                 // row-XOR term for fragment reads

    __shared__ short Ks[2][64 * 64];
    __shared__ short Vs[2][64 * 64];
    __shared__ short Ps[4][16 * 64];

    short8 qf[2][2];
#pragma unroll
    for (int rg = 0; rg < 2; ++rg) {
        const size_t qrow = (size_t)((b * T_) + q0 + rg * 64 + w * 16 + l16) * NQKV + h * 64;
#pragma unroll
        for (int kk = 0; kk < 2; ++kk) {
            short8 raw = *(const short8*)(qkv + qrow + kk * 32 + lq * 8);
            short8 s;
#pragma unroll
            for (int j = 0; j < 8; ++j) s[j] = f2b(0.125f * b2f(raw[j]));
            qf[rg][kk] = s;
        }
    }
    f32x4 acc[2][4];
#pragma unroll
    for (int rg = 0; rg < 2; ++rg)
#pragma unroll
        for (int dt = 0; dt < 4; ++dt) acc[rg][dt] = fz4();
    float m_s[2] = {-1e30f, -1e30f}, l_s[2] = {0.f, 0.f};

    const int nt = 2 * qt + 2;
    auto stage = [&](int bf, int t) {   // 4 gload_lds per thread
        const int k0 = t * 64;
        const size_t kbase = (size_t)((b * T_) + k0) * NQKV + C_ + h * 64;
        const size_t vbase = (size_t)(bh * 64) * 2048 + k0;
#pragma unroll
        for (int p = 0; p < 2; ++p) {
            int c = p * 256 + tid;
            int r = c >> 3;
            int cg = (c & 7) ^ (r & 7);
            load_lds16(qkv + kbase + (size_t)r * NQKV + cg * 8,
                       &Ks[bf][(p * 256 + (tid & ~63)) * 8]);
            load_lds16(vT + vbase + (size_t)r * 2048 + cg * 8,
                       &Vs[bf][(p * 256 + (tid & ~63)) * 8]);
        }
    };

    stage(0, 0);
    for (int t = 0; t < nt; ++t) {
        const int k0 = t * 64;
        if (t + 1 < nt) {
            stage((t + 1) & 1, t + 1);
            asm volatile("s_waitcnt vmcnt(4)" ::: "memory");
        } else {
            asm volatile("s_waitcnt vmcnt(0)" ::: "memory");
        }
        barrier_nodrain();
        const short* Kc = Ks[t & 1];
        const short* Vc = Vs[t & 1];
#pragma unroll
        for (int rg = 0; rg < 2; ++rg) {
            if (rg == 0 && t == nt - 1) continue;   // block-uniform skip
            const int qg = q0 + rg * 64 + w * 16 + l16;
            f32x4 sc[4];
#pragma unroll
            for (int ct = 0; ct < 4; ++ct) sc[ct] = fz4();
            __builtin_amdgcn_s_setprio(1);
#pragma unroll
            for (int kk = 0; kk < 2; ++kk)
#pragma unroll
                for (int ct = 0; ct < 4; ++ct) {
                    short8 ak = *(const short8*)&Kc[(ct * 16 + l16) * 64 + (((kk * 4 + lq) ^ e) * 8)];
                    sc[ct] = __builtin_amdgcn_mfma_f32_16x16x32_bf16(ak, qf[rg][kk], sc[ct], 0, 0, 0);
                }
            __builtin_amdgcn_s_setprio(0);
            if (k0 + 63 > q0 + rg * 64 + w * 16) {
#pragma unroll
                for (int ct = 0; ct < 4; ++ct)
#pragma unroll
                    for (int r = 0; r < 4; ++r)
                        if (k0 + ct * 16 + lq * 4 + r > qg) sc[ct][r] = -1e30f;
            }
            float mx = -1e30f;
#pragma unroll
            for (int ct = 0; ct < 4; ++ct)
#pragma unroll
                for (int r = 0; r < 4; ++r) mx = fmaxf(mx, sc[ct][r]);
            mx = fmaxf(mx, __shfl_xor(mx, 16));
            mx = fmaxf(mx, __shfl_xor(mx, 32));
            float mn = fmaxf(m_s[rg], mx);
            float al = __expf(m_s[rg] - mn);
            m_s[rg] = mn;
            float s0 = 0.f;
#pragma unroll
            for (int ct = 0; ct < 4; ++ct)
#pragma unroll
                for (int r = 0; r < 4; ++r) {
                    float p = __expf(sc[ct][r] - mn);
                    sc[ct][r] = p;
                    s0 += p;
                }
            s0 += __shfl_xor(s0, 16);
            s0 += __shfl_xor(s0, 32);
            l_s[rg] = l_s[rg] * al + s0;
            float albc[4];
#pragma unroll
            for (int r = 0; r < 4; ++r) albc[r] = __shfl(al, lq * 4 + r);
#pragma unroll
            for (int dt = 0; dt < 4; ++dt) {
                f32x4 a4 = acc[rg][dt];
                a4[0] *= albc[0]; a4[1] *= albc[1]; a4[2] *= albc[2]; a4[3] *= albc[3];
                acc[rg][dt] = a4;
            }
#pragma unroll
            for (int ct = 0; ct < 4; ++ct)
#pragma unroll
                for (int r = 0; r < 4; ++r) {
                    int k = ct * 16 + lq * 4 + r;
                    Ps[w][l16 * 64 + (((k >> 3) ^ e) * 8) + (k & 7)] = f2b(sc[ct][r]);
                }
            __builtin_amdgcn_s_setprio(1);
#pragma unroll
            for (int kk = 0; kk < 2; ++kk) {
                short8 pa = *(const short8*)&Ps[w][l16 * 64 + (((kk * 4 + lq) ^ e) * 8)];
#pragma unroll
                for (int dt = 0; dt < 4; ++dt) {
                    short8 bv = *(const short8*)&Vc[(dt * 16 + l16) * 64 + (((kk * 4 + lq) ^ e) * 8)];
                    acc[rg][dt] = __builtin_amdgcn_mfma_f32_16x16x32_bf16(pa, bv, acc[rg][dt], 0, 0, 0);
                }
            }
            __builtin_amdgcn_s_setprio(0);
        }
        barrier_nodrain();
    }
#pragma unroll
    for (int rg = 0; rg < 2; ++rg) {
        float lbc[4];
#pragma unroll
        for (int r = 0; r < 4; ++r) lbc[r] = __shfl(l_s[rg], lq * 4 + r);
#pragma unroll
        for (int r = 0; r < 4; ++r) {
            float inv = 1.0f / lbc[r];
            size_t ob = (size_t)((b * T_) + q0 + rg * 64 + w * 16 + lq * 4 + r) * C_ + h * 64 + l16;
#pragma unroll
            for (int dt = 0; dt < 4; ++dt)
                att[ob + dt * 16] = f2b(acc[rg][dt][r] * inv);
        }
    }
}

extern "C" void kernel_launch(void* const* d_in, const int* in_sizes, int n_in,
                              void* d_out, int out_size, void* d_ws, size_t ws_size,
                              hipStream_t stream) {
    const float* x = (const float*)d_in[0];
    const float* Wqkv = (const float*)d_in[1];
    const float* Wproj = (const float*)d_in[2];
    char* ws = (char*)d_ws;

    short* qkv = (short*)ws;                                     // [0, 48MB)
    short* att = (short*)(ws + (size_t)BT_ * NQKV * 2);          // [48MB, 64MB)
    short* wqb = att;                                            // 6MB, dead before att written
    float2* tab = (float2*)(ws + (size_t)BT_ * NQKV * 2 + (size_t)3 * C_ * C_ * 2); // 512KB @ 54MB
    short* wpb = qkv;                                            // 2MB, qkv dead by then
    short* vT  = (short*)d_out;                                  // d_out[0,16MB): V^T scratch
    short* xb  = (short*)((char*)d_out + ((size_t)BT_ * C_ * 2)); // d_out[16,32MB): x bf16

    // 1) rope table + x,Wqkv -> bf16
    rope_table<<<256, 256, 0, stream>>>(tab);
    cvt_kernel<<<(BT_ * C_) / 2048, 256, 0, stream>>>(x, xb, BT_ * C_);
    cvt_kernel<<<(3 * C_ * C_) / 2048, 256, 0, stream>>>(Wqkv, wqb, 3 * C_ * C_);
    // 2) qkv = xb @ Wqkv^T with fused RoPE (bf16 out)
    dim3 g1(BT_ / 128, NQKV / 256);
    gemm_pipe<0, 1><<<g1, 512, 0, stream>>>(xb, wqb, (void*)qkv, BT_, NQKV, C_, tab);
    // 3) V -> vT (per-(b,h) transpose)
    transpose_v<<<64 * 32, 256, 0, stream>>>(qkv, vT);
    // 4) attention
    attn_mfma<<<B_ * H_ * (T_ / 128), 256, 0, stream>>>(qkv, vT, att);
    // 5) Wproj -> bf16
    cvt_kernel<<<(C_ * C_) / 2048, 256, 0, stream>>>(Wproj, wpb, C_ * C_);
    // 6) out = att @ Wproj^T (fp32 out; overwrites vT/xb scratch)
    dim3 g2(BT_ / 128, C_ / 256);
    gemm_pipe<1, 0><<<g2, 512, 0, stream>>>(att, wpb, d_out, BT_, C_, C_, tab);
}